// Round 8
// baseline (925.501 us; speedup 1.0000x reference)
//
#include <hip/hip_runtime.h>
#include <cstdint>
#include <cstddef>

#define T_ 65536

// ---------------- threefry2x32 (bit-exact vs JAX) ----------------
__device__ __forceinline__ void tf2x32(uint32_t k0, uint32_t k1,
                                       uint32_t& x0, uint32_t& x1) {
  const uint32_t ks[3] = {k0, k1, k0 ^ k1 ^ 0x1BD11BDAu};
  const int R[8] = {13, 15, 26, 6, 17, 29, 16, 24};
  x0 += ks[0]; x1 += ks[1];
#pragma unroll
  for (int i = 0; i < 5; ++i) {
#pragma unroll
    for (int j = 0; j < 4; ++j) {
      const int r = R[(i & 1) * 4 + j];
      x0 += x1;
      x1 = (x1 << r) | (x1 >> (32 - r));
      x1 ^= x0;
    }
    x0 += ks[(i + 1) % 3];
    x1 += ks[(i + 2) % 3] + (uint32_t)(i + 1);
  }
}

__device__ __forceinline__ float gumbel_from_bits(uint32_t b) {
  float u = __uint_as_float((b >> 9) | 0x3f800000u) - 1.0f;
  u = fmaxf(u, 1.17549435e-38f);
  return -logf(-logf(u));
}

// ---------------- coefficient setup (1 block) ----------------
// JAX threefry_partitionable path (default since 0.4.36).
// ws coefs per resonator r: [D1, D2, c1, c2]
__global__ __launch_bounds__(128) void coef_kernel(
    const float* __restrict__ da, const float* __restrict__ fa, const float* __restrict__ ra,
    const float* __restrict__ db, const float* __restrict__ fb, const float* __restrict__ rb,
    const float* __restrict__ dc, const float* __restrict__ fc, const float* __restrict__ rc,
    float* __restrict__ cws) {
  __shared__ float z[128];
  uint32_t keys[3][2];
#pragma unroll
  for (int q = 0; q < 3; ++q) {
    uint32_t x0 = 0u, x1 = (uint32_t)q;
    tf2x32(0u, 42u, x0, x1);
    keys[q][0] = x0; keys[q][1] = x1;
  }
  const float* dl[3] = {da, db, dc};
  const float* fg[3] = {fa, fb, fc};
  const float* rf[3] = {ra, rb, rc};
  const int Ls[3] = {85, 85, 8};
  const int md[3] = {40, 40, 32};
  const int i = threadIdx.x;
  for (int r = 0; r < 3; ++r) {
    const int L = Ls[r];
    z[i] = -3.4e38f;
    __syncthreads();
    if (i < L) {
      uint32_t x0 = 0u, x1 = (uint32_t)i;
      tf2x32(keys[r][0], keys[r][1], x0, x1);
      z[i] = dl[r][i] + gumbel_from_bits(x0 ^ x1);
    }
    __syncthreads();
    if (i == 0) {
      int p = 0; float best = z[0];
      for (int j = 1; j < L; ++j) { float v = z[j]; if (v > best) { best = v; p = j; } }
      const bool lowpass = (r == 2);
      float r0 = rf[r][0], r1 = rf[r][1];
      if (lowpass) { r0 = 1.f / (1.f + expf(-r0)); r1 = 1.f / (1.f + expf(-r1)); }
      else         { r0 = tanhf(r0);               r1 = tanhf(r1); }
      const float k1 = tanhf(r0), k2 = tanhf(r1);
      float a1 = k1 * (1.f - k2);
      const float a2 = fminf(fmaxf(k2, -0.999f), 0.999f);
      const float bnd = 0.999f - fabsf(a2);
      a1 = fminf(fmaxf(a1, -bnd), bnd);
      const float g = powf(1.f / (1.f + expf(-fg[r][0])), 0.45f);
      cws[r * 4 + 0] = (float)(md[r] + p + 1);
      cws[r * 4 + 1] = (float)(md[r] + ((p + 1) % L) + 1);
      cws[r * 4 + 2] = a1 * g;
      cws[r * 4 + 3] = a2 * g;
    }
    __syncthreads();
  }
}

// ---------------- power-cycle-phase prefix sum (fp64 block scan) ----------------
__global__ __launch_bounds__(1024) void pcp_kernel(const float* __restrict__ f0,
                                                   float* __restrict__ pcp) {
  __shared__ double sm[1024];
  const int b = blockIdx.x;
  const int tid = threadIdx.x;
  const float* src = f0 + (size_t)b * T_;
  const int base = tid * 64;
  double loc = 0.0;
  for (int k = 0; k < 64; ++k) {
    loc += 6.283185307179586 * (double)src[base + k] / 48000.0;
  }
  sm[tid] = loc;
  __syncthreads();
  for (int off = 1; off < 1024; off <<= 1) {
    double v = (tid >= off) ? sm[tid - off] : 0.0;
    __syncthreads();
    sm[tid] += v;
    __syncthreads();
  }
  double run = (tid > 0) ? sm[tid - 1] : 0.0;
  float* dst = pcp + (size_t)b * T_;
  for (int k = 0; k < 64; ++k) {
    run += 6.283185307179586 * (double)src[base + k] / 48000.0;
    dst[base + k] = (float)(run * 0.5);
  }
}

// ---------------- harmonic synth + banks (memory-bound) ----------------
__global__ __launch_bounds__(256) void synth_kernel(
    const float* __restrict__ amps,   // (B,512,T)
    const float* __restrict__ fmg,    // (B,1,T)
    const float* __restrict__ cps,    // (B,16,T)
    const float* __restrict__ nba,    // (B,32,T)
    const float* __restrict__ nps,    // (B,2,T)
    const float* __restrict__ npg,    // (B,1,T)
    const float* __restrict__ fng,    // (B,1,T)
    const float* __restrict__ bands,  // (32,T)
    const float* __restrict__ pcp,    // (B,T) ws
    float* __restrict__ bank_a, float* __restrict__ bank_b) {
  const float TPF = 6.283185307179586f;
  const int gid = blockIdx.x * 256 + threadIdx.x;
  const int b = gid >> 15;
  const int t = (gid & 32767) * 2;
  const size_t bt = (size_t)b * T_ + t;
  const float p0 = pcp[bt], p1 = pcp[bt + 1];
  const float fm0 = fmg[bt], fm1 = fmg[bt + 1];

  float nse0 = 0.f, nse1 = 0.f;
  for (int n = 0; n < 32; ++n) {
    const float2 a = *(const float2*)(nba + ((size_t)b * 32 + n) * T_ + t);
    const float2 w = *(const float2*)(bands + (size_t)n * T_ + t);
    nse0 += a.x * w.x; nse1 += a.y * w.y;
  }

  const int order[8] = {0, 4, 3, 7, 5, 2, 6, 1};
  float ha0 = 0, ha1 = 0, hb0 = 0, hb1 = 0;
#pragma unroll
  for (int c = 0; c < 8; ++c) {
    const float ang = ((float)order[c] / 8.0f) * TPF;
    float s0 = p0 + ang; if (s0 >= TPF) s0 -= TPF;
    float s1 = p1 + ang; if (s1 >= TPF) s1 -= TPF;
    const float th0 = TPF * powf(s0 / TPF, fm0);
    const float th1 = TPF * powf(s1 / TPF, fm1);
    float sn0, cs0, sn1, cs1;
    sincosf(th0, &sn0, &cs0);
    sincosf(th1, &sn1, &cs1);
    float sp0 = 0.f, sc0 = sn0, sp1 = 0.f, sc1 = sn1;
    const float tc0 = 2.f * cs0, tc1 = 2.f * cs1;
    float acc0 = 0.f, acc1 = 0.f;
    const float* ap = amps + ((size_t)b * 512 + (size_t)c * 64) * T_ + t;
#pragma unroll 4
    for (int h = 0; h < 64; ++h) {
      const float2 a = *(const float2*)(ap + (size_t)h * T_);
      acc0 += a.x * sc0; acc1 += a.y * sc1;
      const float nx0 = tc0 * sc0 - sp0; sp0 = sc0; sc0 = nx0;
      const float nx1 = tc1 * sc1 - sp1; sp1 = sc1; sc1 = nx1;
    }
    const float2 al = *(const float2*)(cps + ((size_t)b * 16 + c) * T_ + t);
    const float2 be = *(const float2*)(cps + ((size_t)b * 16 + 8 + c) * T_ + t);
    const float env0 = (1.f - expf(-al.x * s0)) * expf(-be.x * s0);
    const float env1 = (1.f - expf(-al.y * s1)) * expf(-be.y * s1);
    const float hh0 = -acc0 * env0 * 10.f;
    const float hh1 = -acc1 * env1 * 10.f;
    if (c < 4) { ha0 += hh0; ha1 += hh1; } else { hb0 += hh0; hb1 += hh1; }
  }

  const float g0 = npg[bt], g1 = npg[bt + 1];
  const float fl0 = fng[bt], fl1 = fng[bt + 1];
  const float na0 = nps[(size_t)b * 2 * T_ + t],     na1 = nps[(size_t)b * 2 * T_ + t + 1];
  const float nb0 = nps[((size_t)b * 2 + 1) * T_ + t], nb1 = nps[((size_t)b * 2 + 1) * T_ + t + 1];
  float q0 = p0; if (q0 >= TPF) q0 -= TPF;
  float q1 = p1; if (q1 >= TPF) q1 -= TPF;
  const float ne0 = (1.f - expf(-na0 * q0)) * expf(-nb0 * q0);
  const float ne1 = (1.f - expf(-na1 * q1)) * expf(-nb1 * q1);
  const float com0 = nse0 * (ne0 * g0 + fl0 * 0.3f);
  const float com1 = nse1 * (ne1 * g1 + fl1 * 0.3f);
  const float K0 = nse0 * (g0 + fl0) * 0.7f;
  const float K1 = nse1 * (g1 + fl1) * 0.7f;
  *(float2*)(bank_a + bt) = make_float2(ha0 * (1.f + K0) + 4.f * com0,
                                        ha1 * (1.f + K1) + 4.f * com1);
  *(float2*)(bank_b + bt) = make_float2(hb0 * (1.f + K0) + 4.f * com0,
                                        hb1 * (1.f + K1) + 4.f * com1);
}

// ---------------- 2-tap comb resonator: LDS-staged wave-sync scan ------------
// Rounds 3-7 post-mortem: the compiler re-sinks register prefetch loads to
// their uses (VGPR never rose), re-serializing to one HBM latency per step.
// Fix: stage input via __builtin_amdgcn_global_load_lds (side-effecting DMA,
// cannot be sunk; data never occupies VGPRs). Double-buffered segments of
// KC<=1024 samples; per phase ONE inline-asm vmcnt(0) drain (staging was
// issued a full phase earlier -> drain is cheap), then issue next segment's
// DMA, then K steps reading xv from LDS (1-step register prefetch). Taps stay
// in __shfl'd history registers h1..h4. KC forced to a multiple of 4 so DMA
// reads are 16B-aligned and the tail clamp only affects t >= T_.
__device__ __forceinline__ void gld16(const float* g, float* l) {
  __builtin_amdgcn_global_load_lds((const __attribute__((address_space(1))) void*)g,
                                   (__attribute__((address_space(3))) void*)l, 16, 0, 0);
}

#define BS_ 1088  // LDS buffer stride in floats

template <bool TWO_IN>
__device__ __forceinline__ void lds_scan(const float* __restrict__ x1,
                                         const float* __restrict__ x2,
                                         float* __restrict__ yo,
                                         const float* __restrict__ cf,
                                         float* __restrict__ dump,
                                         float* __restrict__ sm) {
  const int D1 = (int)cf[0];
  const int D2 = (int)cf[1];
  const float c1 = cf[2], c2 = cf[3];
  const int W = (D1 < D2) ? D1 : D2;      // >= 33
  const int C = (W < 64) ? W : 64;        // chunk size, 33..64
  const int o = threadIdx.x & 63;
  const int k1 = (D1 - o + C - 1) / C;    // history chunk index, 1..4 (lanes < C)
  const int s1 = o - D1 + k1 * C;         // source lane, 0..C-1 (lanes < C)
  const int k2 = (D2 - o + C - 1) / C;
  const int s2 = o - D2 + k2 * C;
  // steps per phase: K*C <= 1024 and K*C multiple of 4 (alignment)
  int K = 1024 / C;
  if (C % 4 != 0) K &= (C % 2 == 0) ? ~1 : ~3;   // K in [16,31]
  const int KC = K * C;
  const int ni = (KC + 255) >> 8;         // 16B-DMA instructions per input
  const int S = (T_ + C - 1) / C;
  const int nph = (S + K - 1) / K;
  const bool act = (o < C);

  float h1 = 0.f, h2 = 0.f, h3 = 0.f, h4 = 0.f;

  // stage segment seg into buffer parity q (clamped, aligned, branch-free)
  auto stage = [&](int seg, int q) {
    const int bt = seg * KC;
    for (int i = 0; i < ni; ++i) {
      int idx = bt + i * 256 + (o << 2);
      idx = (idx <= T_ - 4) ? idx : (T_ - 4);
      gld16(x1 + idx, sm + q * BS_ + i * 256);
      if (TWO_IN) gld16(x2 + idx, sm + 2 * BS_ + q * BS_ + i * 256);
    }
  };

  stage(0, 0);
  for (int p = 0; p < nph; ++p) {
    const int q = p & 1;
    // buffer q's staging was issued one full phase ago -> cheap drain;
    // guarantees correctness independent of compiler waitcnt choices.
    asm volatile("s_waitcnt vmcnt(0)" ::: "memory");
    __builtin_amdgcn_sched_barrier(0);
    stage(p + 1, q ^ 1);
    const float* b1 = sm + q * BS_;
    const float* b2 = sm + 2 * BS_ + q * BS_;
    float xv1 = b1[o];
    float xv2 = TWO_IN ? b2[o] : 0.f;
    int t = p * KC + o;
    for (int l = 0; l < K; ++l) {
      const int ln = (l + 1 < K) ? (l + 1) : (K - 1);
      const float xn1 = b1[ln * C + o];                 // prefetch next xv
      const float xn2 = TWO_IN ? b2[ln * C + o] : 0.f;
      const float xv = TWO_IN ? (xv1 + xv2) : xv1;
      const float a1v = __shfl(h1, s1, 64);
      const float a2v = __shfl(h2, s1, 64);
      const float a3v = __shfl(h3, s1, 64);
      const float a4v = __shfl(h4, s1, 64);
      const float v1 = (k1 == 1) ? a1v : (k1 == 2) ? a2v : (k1 == 3) ? a3v : a4v;
      const float b1v = __shfl(h1, s2, 64);
      const float b2v = __shfl(h2, s2, 64);
      const float b3v = __shfl(h3, s2, 64);
      const float b4v = __shfl(h4, s2, 64);
      const float v2 = (k2 == 1) ? b1v : (k2 == 2) ? b2v : (k2 == 3) ? b3v : b4v;
      const float y = xv - (c1 * v1 + c2 * v2);
      float* sp = (act && t < T_) ? (yo + t) : (dump + o);  // branch-free store
      *sp = y;
      h4 = h3; h3 = h2; h2 = h1; h1 = y;
      xv1 = xn1; xv2 = xn2;
      t += C;
    }
  }
}

__global__ __launch_bounds__(64) void res_ab_kernel(
    const float* __restrict__ BA, const float* __restrict__ BB,
    float* __restrict__ RA, float* __restrict__ RB, const float* __restrict__ CW,
    float* __restrict__ dump) {
  __shared__ float sm[4 * BS_];
  const int r = blockIdx.x >> 1;
  const int b = blockIdx.x & 1;
  const float* x = (r == 0 ? BA : BB) + (size_t)b * T_;
  float* y = (r == 0 ? RA : RB) + (size_t)b * T_;
  lds_scan<false>(x, nullptr, y, CW + r * 4, dump + blockIdx.x * 64, sm);
}

__global__ __launch_bounds__(64) void res_c_kernel(
    const float* __restrict__ RA, const float* __restrict__ RB,
    float* __restrict__ out, const float* __restrict__ CW,
    float* __restrict__ dump) {
  __shared__ float sm[4 * BS_];
  const int b = blockIdx.x;
  lds_scan<true>(RA + (size_t)b * T_, RB + (size_t)b * T_, out + (size_t)b * T_,
                 CW + 8, dump + blockIdx.x * 64, sm);
}

// ---------------- launch ----------------
extern "C" void kernel_launch(void* const* d_in, const int* in_sizes, int n_in,
                              void* d_out, int out_size, void* d_ws, size_t ws_size,
                              hipStream_t stream) {
  const float* f0    = (const float*)d_in[0];
  const float* amps  = (const float*)d_in[1];
  const float* fmg   = (const float*)d_in[2];
  const float* cps   = (const float*)d_in[4];
  const float* nba   = (const float*)d_in[5];
  const float* nps   = (const float*)d_in[6];
  const float* npg   = (const float*)d_in[7];
  const float* fng   = (const float*)d_in[8];
  const float* bands = (const float*)d_in[9];
  const float* da  = (const float*)d_in[10];
  const float* fga = (const float*)d_in[11];
  const float* ra  = (const float*)d_in[12];
  const float* db  = (const float*)d_in[13];
  const float* fgb = (const float*)d_in[14];
  const float* rb  = (const float*)d_in[15];
  const float* dc  = (const float*)d_in[16];
  const float* fgc = (const float*)d_in[17];
  const float* rc  = (const float*)d_in[18];
  float* out = (float*)d_out;
  float* ws  = (float*)d_ws;

  float* W0 = ws;              // pcp, then reused as res_a
  float* W1 = ws + 131072;     // bank_a
  float* W2 = ws + 262144;     // bank_b
  float* W3 = ws + 393216;     // res_b
  float* CW = ws + 524288;     // coefficients (16 floats)
  float* DP = ws + 524320;     // dump scratch (4 blocks * 64 lanes)

  pcp_kernel<<<2, 1024, 0, stream>>>(f0, W0);
  coef_kernel<<<1, 128, 0, stream>>>(da, fga, ra, db, fgb, rb, dc, fgc, rc, CW);
  synth_kernel<<<256, 256, 0, stream>>>(amps, fmg, cps, nba, nps, npg, fng, bands,
                                        W0, W1, W2);
  res_ab_kernel<<<4, 64, 0, stream>>>(W1, W2, W0, W3, CW, DP);
  res_c_kernel<<<2, 64, 0, stream>>>(W0, W3, out, CW, DP);
}

// Round 9
// 318.410 us; speedup vs baseline: 2.9066x; 2.9066x over previous
//
#include <hip/hip_runtime.h>
#include <cstdint>
#include <cstddef>

#define T_ 65536

// ---------------- threefry2x32 (bit-exact vs JAX) ----------------
__device__ __forceinline__ void tf2x32(uint32_t k0, uint32_t k1,
                                       uint32_t& x0, uint32_t& x1) {
  const uint32_t ks[3] = {k0, k1, k0 ^ k1 ^ 0x1BD11BDAu};
  const int R[8] = {13, 15, 26, 6, 17, 29, 16, 24};
  x0 += ks[0]; x1 += ks[1];
#pragma unroll
  for (int i = 0; i < 5; ++i) {
#pragma unroll
    for (int j = 0; j < 4; ++j) {
      const int r = R[(i & 1) * 4 + j];
      x0 += x1;
      x1 = (x1 << r) | (x1 >> (32 - r));
      x1 ^= x0;
    }
    x0 += ks[(i + 1) % 3];
    x1 += ks[(i + 2) % 3] + (uint32_t)(i + 1);
  }
}

__device__ __forceinline__ float gumbel_from_bits(uint32_t b) {
  float u = __uint_as_float((b >> 9) | 0x3f800000u) - 1.0f;
  u = fmaxf(u, 1.17549435e-38f);
  return -logf(-logf(u));
}

// ---------------- coefficient setup (1 block) ----------------
// JAX threefry_partitionable path (default since 0.4.36).
// Per resonator r (stride 32 floats in cws):
//   [0..4]   recurrence tap delays E_j = (4-j)D1 + jD2   (>= 4*min(D1,D2) >= 132)
//   [5..9]   recurrence tap coeffs F_j = C(4,j) c1^(4-j) c2^j   (y = x'' + SUM F_j y[t-E_j])
//   [10..18] feedforward delays d_k, [19..27] feedforward coeffs n_k
//            (x'' = x + SUM n_k x[t-d_k], from N = 1 - P + P^2 - P^3)
__global__ __launch_bounds__(128) void coef_kernel(
    const float* __restrict__ da, const float* __restrict__ fa, const float* __restrict__ ra,
    const float* __restrict__ db, const float* __restrict__ fb, const float* __restrict__ rb,
    const float* __restrict__ dc, const float* __restrict__ fc, const float* __restrict__ rc,
    float* __restrict__ cws) {
  __shared__ float z[128];
  uint32_t keys[3][2];
#pragma unroll
  for (int q = 0; q < 3; ++q) {
    uint32_t x0 = 0u, x1 = (uint32_t)q;
    tf2x32(0u, 42u, x0, x1);
    keys[q][0] = x0; keys[q][1] = x1;
  }
  const float* dl[3] = {da, db, dc};
  const float* fg[3] = {fa, fb, fc};
  const float* rf[3] = {ra, rb, rc};
  const int Ls[3] = {85, 85, 8};
  const int md[3] = {40, 40, 32};
  const int i = threadIdx.x;
  for (int r = 0; r < 3; ++r) {
    const int L = Ls[r];
    z[i] = -3.4e38f;
    __syncthreads();
    if (i < L) {
      uint32_t x0 = 0u, x1 = (uint32_t)i;
      tf2x32(keys[r][0], keys[r][1], x0, x1);
      z[i] = dl[r][i] + gumbel_from_bits(x0 ^ x1);
    }
    __syncthreads();
    if (i == 0) {
      int p = 0; float best = z[0];
      for (int j = 1; j < L; ++j) { float v = z[j]; if (v > best) { best = v; p = j; } }
      const bool lowpass = (r == 2);
      float r0 = rf[r][0], r1 = rf[r][1];
      if (lowpass) { r0 = 1.f / (1.f + expf(-r0)); r1 = 1.f / (1.f + expf(-r1)); }
      else         { r0 = tanhf(r0);               r1 = tanhf(r1); }
      const float k1 = tanhf(r0), k2 = tanhf(r1);
      float a1 = k1 * (1.f - k2);
      const float a2 = fminf(fmaxf(k2, -0.999f), 0.999f);
      const float bnd = 0.999f - fabsf(a2);
      a1 = fminf(fmaxf(a1, -bnd), bnd);
      const float g = powf(1.f / (1.f + expf(-fg[r][0])), 0.45f);
      const int D1 = md[r] + p + 1;
      const int D2 = md[r] + ((p + 1) % L) + 1;
      const float C1 = a1 * g;           // y = x - C1 y[t-D1] - C2 y[t-D2]
      const float C2 = a2 * g;
      float* cw = cws + r * 32;
      // recurrence: 1 - P^4,  P = C1 z^-D1 + C2 z^-D2
      const float bin4[5] = {1.f, 4.f, 6.f, 4.f, 1.f};
      const float c1p[5] = {1.f, C1, C1*C1, C1*C1*C1, C1*C1*C1*C1};
      const float c2p[5] = {1.f, C2, C2*C2, C2*C2*C2, C2*C2*C2*C2};
      for (int j = 0; j < 5; ++j) {
        cw[j]     = (float)((4 - j) * D1 + j * D2);
        cw[5 + j] = bin4[j] * c1p[4 - j] * c2p[j];
      }
      // feedforward N = 1 - P + P^2 - P^3
      const int   fd[9] = {D1, D2, 2*D1, D1+D2, 2*D2, 3*D1, 2*D1+D2, D1+2*D2, 3*D2};
      const float fn[9] = {-C1, -C2, C1*C1, 2.f*C1*C2, C2*C2,
                           -C1*C1*C1, -3.f*C1*C1*C2, -3.f*C1*C2*C2, -C2*C2*C2};
      for (int k = 0; k < 9; ++k) {
        cw[10 + k] = (float)fd[k];
        cw[19 + k] = fn[k];
      }
    }
    __syncthreads();
  }
}

// ---------------- power-cycle-phase prefix sum (fp64 block scan) ----------------
__global__ __launch_bounds__(1024) void pcp_kernel(const float* __restrict__ f0,
                                                   float* __restrict__ pcp) {
  __shared__ double sm[1024];
  const int b = blockIdx.x;
  const int tid = threadIdx.x;
  const float* src = f0 + (size_t)b * T_;
  const int base = tid * 64;
  double loc = 0.0;
  for (int k = 0; k < 64; ++k) {
    loc += 6.283185307179586 * (double)src[base + k] / 48000.0;
  }
  sm[tid] = loc;
  __syncthreads();
  for (int off = 1; off < 1024; off <<= 1) {
    double v = (tid >= off) ? sm[tid - off] : 0.0;
    __syncthreads();
    sm[tid] += v;
    __syncthreads();
  }
  double run = (tid > 0) ? sm[tid - 1] : 0.0;
  float* dst = pcp + (size_t)b * T_;
  for (int k = 0; k < 64; ++k) {
    run += 6.283185307179586 * (double)src[base + k] / 48000.0;
    dst[base + k] = (float)(run * 0.5);
  }
}

// ---------------- harmonic synth + banks (memory-bound) ----------------
__global__ __launch_bounds__(256) void synth_kernel(
    const float* __restrict__ amps,   // (B,512,T)
    const float* __restrict__ fmg,    // (B,1,T)
    const float* __restrict__ cps,    // (B,16,T)
    const float* __restrict__ nba,    // (B,32,T)
    const float* __restrict__ nps,    // (B,2,T)
    const float* __restrict__ npg,    // (B,1,T)
    const float* __restrict__ fng,    // (B,1,T)
    const float* __restrict__ bands,  // (32,T)
    const float* __restrict__ pcp,    // (B,T) ws
    float* __restrict__ bank_a, float* __restrict__ bank_b) {
  const float TPF = 6.283185307179586f;
  const int gid = blockIdx.x * 256 + threadIdx.x;
  const int b = gid >> 15;
  const int t = (gid & 32767) * 2;
  const size_t bt = (size_t)b * T_ + t;
  const float p0 = pcp[bt], p1 = pcp[bt + 1];
  const float fm0 = fmg[bt], fm1 = fmg[bt + 1];

  float nse0 = 0.f, nse1 = 0.f;
  for (int n = 0; n < 32; ++n) {
    const float2 a = *(const float2*)(nba + ((size_t)b * 32 + n) * T_ + t);
    const float2 w = *(const float2*)(bands + (size_t)n * T_ + t);
    nse0 += a.x * w.x; nse1 += a.y * w.y;
  }

  const int order[8] = {0, 4, 3, 7, 5, 2, 6, 1};
  float ha0 = 0, ha1 = 0, hb0 = 0, hb1 = 0;
#pragma unroll
  for (int c = 0; c < 8; ++c) {
    const float ang = ((float)order[c] / 8.0f) * TPF;
    float s0 = p0 + ang; if (s0 >= TPF) s0 -= TPF;
    float s1 = p1 + ang; if (s1 >= TPF) s1 -= TPF;
    const float th0 = TPF * powf(s0 / TPF, fm0);
    const float th1 = TPF * powf(s1 / TPF, fm1);
    float sn0, cs0, sn1, cs1;
    sincosf(th0, &sn0, &cs0);
    sincosf(th1, &sn1, &cs1);
    float sp0 = 0.f, sc0 = sn0, sp1 = 0.f, sc1 = sn1;
    const float tc0 = 2.f * cs0, tc1 = 2.f * cs1;
    float acc0 = 0.f, acc1 = 0.f;
    const float* ap = amps + ((size_t)b * 512 + (size_t)c * 64) * T_ + t;
#pragma unroll 4
    for (int h = 0; h < 64; ++h) {
      const float2 a = *(const float2*)(ap + (size_t)h * T_);
      acc0 += a.x * sc0; acc1 += a.y * sc1;
      const float nx0 = tc0 * sc0 - sp0; sp0 = sc0; sc0 = nx0;
      const float nx1 = tc1 * sc1 - sp1; sp1 = sc1; sc1 = nx1;
    }
    const float2 al = *(const float2*)(cps + ((size_t)b * 16 + c) * T_ + t);
    const float2 be = *(const float2*)(cps + ((size_t)b * 16 + 8 + c) * T_ + t);
    const float env0 = (1.f - expf(-al.x * s0)) * expf(-be.x * s0);
    const float env1 = (1.f - expf(-al.y * s1)) * expf(-be.y * s1);
    const float hh0 = -acc0 * env0 * 10.f;
    const float hh1 = -acc1 * env1 * 10.f;
    if (c < 4) { ha0 += hh0; ha1 += hh1; } else { hb0 += hh0; hb1 += hh1; }
  }

  const float g0 = npg[bt], g1 = npg[bt + 1];
  const float fl0 = fng[bt], fl1 = fng[bt + 1];
  const float na0 = nps[(size_t)b * 2 * T_ + t],     na1 = nps[(size_t)b * 2 * T_ + t + 1];
  const float nb0 = nps[((size_t)b * 2 + 1) * T_ + t], nb1 = nps[((size_t)b * 2 + 1) * T_ + t + 1];
  float q0 = p0; if (q0 >= TPF) q0 -= TPF;
  float q1 = p1; if (q1 >= TPF) q1 -= TPF;
  const float ne0 = (1.f - expf(-na0 * q0)) * expf(-nb0 * q0);
  const float ne1 = (1.f - expf(-na1 * q1)) * expf(-nb1 * q1);
  const float com0 = nse0 * (ne0 * g0 + fl0 * 0.3f);
  const float com1 = nse1 * (ne1 * g1 + fl1 * 0.3f);
  const float K0 = nse0 * (g0 + fl0) * 0.7f;
  const float K1 = nse1 * (g1 + fl1) * 0.7f;
  *(float2*)(bank_a + bt) = make_float2(ha0 * (1.f + K0) + 4.f * com0,
                                        ha1 * (1.f + K1) + 4.f * com1);
  *(float2*)(bank_b + bt) = make_float2(hb0 * (1.f + K0) + 4.f * com0,
                                        hb1 * (1.f + K1) + 4.f * com1);
}

// ---------------- feedforward prep: x'' = x + SUM n_k x[t-d_k] --------------
__global__ __launch_bounds__(256) void prep_ab_kernel(
    const float* __restrict__ BA, const float* __restrict__ BB,
    const float* __restrict__ CW, float* __restrict__ XA, float* __restrict__ XB) {
  const int idx = blockIdx.x * 256 + threadIdx.x;   // 0..262143
  const int t = idx & (T_ - 1);
  const int s = idx >> 16;                           // 0..3
  const int r = s >> 1, b = s & 1;
  const float* xin = (r == 0 ? BA : BB) + (size_t)b * T_;
  float* xout = (r == 0 ? XA : XB) + (size_t)b * T_;
  const float* cw = CW + r * 32;
  float acc = xin[t];
#pragma unroll
  for (int k = 0; k < 9; ++k) {
    const int d = (int)cw[10 + k];
    const float n = cw[19 + k];
    const int tc = t - d;
    const float u = xin[tc >= 0 ? tc : 0];
    acc += (tc >= 0) ? n * u : 0.f;
  }
  xout[t] = acc;
}

__global__ __launch_bounds__(256) void prep_c_kernel(
    const float* __restrict__ RA, const float* __restrict__ RB,
    const float* __restrict__ CW, float* __restrict__ XC) {
  const int idx = blockIdx.x * 256 + threadIdx.x;   // 0..131071
  const int t = idx & (T_ - 1);
  const int b = idx >> 16;
  const float* ya = RA + (size_t)b * T_;
  const float* yb = RB + (size_t)b * T_;
  const float* cw = CW + 64;
  float acc = ya[t] + yb[t];
#pragma unroll
  for (int k = 0; k < 9; ++k) {
    const int d = (int)cw[10 + k];
    const float n = cw[19 + k];
    const int tc = t - d;
    const float u = ya[tc >= 0 ? tc : 0] + yb[tc >= 0 ? tc : 0];
    acc += (tc >= 0) ? n * u : 0.f;
  }
  XC[idx] = acc;
}

// ---------------- resonator scan: delay-quadrupled 5-tap recurrence ----------
// One wave per filter. C = 64 lanes, S = 1024 steps (T = 1024*64 exactly).
// All tap delays E_j >= 132 > 2*64 => each tap targets a sample written at
// least one full step before the reading step => taps live in a shared LDS
// ring (1024 floats), read ONE STEP AHEAD (latency hidden), conflict-free
// (consecutive lanes -> consecutive addresses). No shuffles, no selects.
// x'' staged HBM->LDS via global_load_lds in 1024-sample phases (16 steps),
// double-buffered, one vmcnt drain per phase.
__device__ __forceinline__ void gld16(const float* g, float* l) {
  __builtin_amdgcn_global_load_lds((const __attribute__((address_space(1))) void*)g,
                                   (__attribute__((address_space(3))) void*)l, 16, 0, 0);
}

__device__ __forceinline__ void poly_scan(const float* __restrict__ x,
                                          float* __restrict__ y,
                                          const float* __restrict__ cf,
                                          float* __restrict__ sm) {
  const int o = threadIdx.x & 63;
  const int e0 = (int)cf[0], e1 = (int)cf[1], e2 = (int)cf[2],
            e3 = (int)cf[3], e4 = (int)cf[4];
  const float fc0 = cf[5], fc1 = cf[6], fc2 = cf[7], fc3 = cf[8], fc4 = cf[9];
  float* ring = sm;          // 1024 floats
  float* st   = sm + 1024;   // 2 x 1024 floats staging

  // zero ring (zero initial conditions; unwrapped slots stay zero until their
  // own write time, so early out-of-range taps correctly read 0)
#pragma unroll
  for (int i = 0; i < 16; ++i) ring[o + i * 64] = 0.f;

  // stage segment 0 -> buffer 0
  {
    const float* g = x + (o << 2);
    gld16(g, st); gld16(g + 256, st + 256);
    gld16(g + 512, st + 512); gld16(g + 768, st + 768);
  }

  // prime taps for t = o (reads of pre-zeroed region)
  float v0 = ring[(o - e0) & 1023];
  float v1 = ring[(o - e1) & 1023];
  float v2 = ring[(o - e2) & 1023];
  float v3 = ring[(o - e3) & 1023];
  float v4 = ring[(o - e4) & 1023];

  int t = o;
  for (int ph = 0; ph < 64; ++ph) {
    const int q = ph & 1;
    // buffer q's DMA was issued a full phase ago -> cheap drain; also drains
    // previous phase's y stores. Guarantees st[q] is valid below.
    asm volatile("s_waitcnt vmcnt(0)" ::: "memory");
    if (ph < 63) {   // uniform branch: issue next segment into the other buffer
      const float* g = x + (ph + 1) * 1024 + (o << 2);
      float* l = st + (q ^ 1) * 1024;
      gld16(g, l); gld16(g + 256, l + 256);
      gld16(g + 512, l + 512); gld16(g + 768, l + 768);
    }
    float xv = st[q * 1024 + o];
#pragma unroll
    for (int l = 0; l < 16; ++l) {
      float yv = xv;
      yv = fmaf(fc0, v0, yv);
      yv = fmaf(fc1, v1, yv);
      yv = fmaf(fc2, v2, yv);
      yv = fmaf(fc3, v3, yv);
      yv = fmaf(fc4, v4, yv);
      ring[t & 1023] = yv;       // in-order DS: visible to later reads
      y[t] = yv;                 // always in-bounds (T % 64 == 0)
      // prefetch taps for step t+64 (targets written >= 1 step ago: E >= 132)
      v0 = ring[(t + 64 - e0) & 1023];
      v1 = ring[(t + 64 - e1) & 1023];
      v2 = ring[(t + 64 - e2) & 1023];
      v3 = ring[(t + 64 - e3) & 1023];
      v4 = ring[(t + 64 - e4) & 1023];
      if (l < 15) xv = st[q * 1024 + (l + 1) * 64 + o];
      t += 64;
    }
  }
}

__global__ __launch_bounds__(64) void res_ab_kernel(
    const float* __restrict__ XA, const float* __restrict__ XB,
    float* __restrict__ RA, float* __restrict__ RB, const float* __restrict__ CW) {
  __shared__ float sm[3072];
  const int r = blockIdx.x >> 1;
  const int b = blockIdx.x & 1;
  poly_scan((r == 0 ? XA : XB) + (size_t)b * T_,
            (r == 0 ? RA : RB) + (size_t)b * T_, CW + r * 32, sm);
}

__global__ __launch_bounds__(64) void res_c_kernel(
    const float* __restrict__ XC, float* __restrict__ out,
    const float* __restrict__ CW) {
  __shared__ float sm[3072];
  poly_scan(XC + (size_t)blockIdx.x * T_, out + (size_t)blockIdx.x * T_,
            CW + 64, sm);
}

// ---------------- launch ----------------
extern "C" void kernel_launch(void* const* d_in, const int* in_sizes, int n_in,
                              void* d_out, int out_size, void* d_ws, size_t ws_size,
                              hipStream_t stream) {
  const float* f0    = (const float*)d_in[0];
  const float* amps  = (const float*)d_in[1];
  const float* fmg   = (const float*)d_in[2];
  const float* cps   = (const float*)d_in[4];
  const float* nba   = (const float*)d_in[5];
  const float* nps   = (const float*)d_in[6];
  const float* npg   = (const float*)d_in[7];
  const float* fng   = (const float*)d_in[8];
  const float* bands = (const float*)d_in[9];
  const float* da  = (const float*)d_in[10];
  const float* fga = (const float*)d_in[11];
  const float* ra  = (const float*)d_in[12];
  const float* db  = (const float*)d_in[13];
  const float* fgb = (const float*)d_in[14];
  const float* rb  = (const float*)d_in[15];
  const float* dc  = (const float*)d_in[16];
  const float* fgc = (const float*)d_in[17];
  const float* rc  = (const float*)d_in[18];
  float* out = (float*)d_out;
  float* ws  = (float*)d_ws;

  // slots of 131072 floats (B*T):
  float* S0 = ws;              // pcp  -> later XA (x''_a)
  float* S1 = ws + 131072;     // bank_a -> later RA (res_a)
  float* S2 = ws + 262144;     // bank_b -> later RB (res_b)
  float* S3 = ws + 393216;     // XB (x''_b) -> later XC (x''_c)
  float* CW = ws + 524288;     // coefficients (96 floats)

  pcp_kernel<<<2, 1024, 0, stream>>>(f0, S0);
  coef_kernel<<<1, 128, 0, stream>>>(da, fga, ra, db, fgb, rb, dc, fgc, rc, CW);
  synth_kernel<<<256, 256, 0, stream>>>(amps, fmg, cps, nba, nps, npg, fng, bands,
                                        S0, S1, S2);
  // feedforward for banks: XA<-S0 (pcp dead), XB<-S3; reads banks S1,S2
  prep_ab_kernel<<<1024, 256, 0, stream>>>(S1, S2, CW, S0, S3);
  // scans: RA->S1 (bank_a dead), RB->S2 (bank_b dead); reads XA=S0, XB=S3
  res_ab_kernel<<<4, 64, 0, stream>>>(S0, S3, S1, S2, CW);
  // feedforward for c: XC<-S3 (XB dead); reads RA=S1, RB=S2
  prep_c_kernel<<<512, 256, 0, stream>>>(S1, S2, CW, S3);
  res_c_kernel<<<2, 64, 0, stream>>>(S3, out, CW);
}

// Round 10
// 297.568 us; speedup vs baseline: 3.1102x; 1.0700x over previous
//
#include <hip/hip_runtime.h>
#include <cstdint>
#include <cstddef>

#define T_ 65536

// ---------------- threefry2x32 (bit-exact vs JAX) ----------------
__device__ __forceinline__ void tf2x32(uint32_t k0, uint32_t k1,
                                       uint32_t& x0, uint32_t& x1) {
  const uint32_t ks[3] = {k0, k1, k0 ^ k1 ^ 0x1BD11BDAu};
  const int R[8] = {13, 15, 26, 6, 17, 29, 16, 24};
  x0 += ks[0]; x1 += ks[1];
#pragma unroll
  for (int i = 0; i < 5; ++i) {
#pragma unroll
    for (int j = 0; j < 4; ++j) {
      const int r = R[(i & 1) * 4 + j];
      x0 += x1;
      x1 = (x1 << r) | (x1 >> (32 - r));
      x1 ^= x0;
    }
    x0 += ks[(i + 1) % 3];
    x1 += ks[(i + 2) % 3] + (uint32_t)(i + 1);
  }
}

__device__ __forceinline__ float gumbel_from_bits(uint32_t b) {
  float u = __uint_as_float((b >> 9) | 0x3f800000u) - 1.0f;
  u = fmaxf(u, 1.17549435e-38f);
  return -logf(-logf(u));
}

// ---------------- coefficient setup (1 block) ----------------
// JAX threefry_partitionable path (default since 0.4.36).
// Per resonator r (stride 32 floats in cws):
//   [0..4]   recurrence tap delays E_j = (4-j)D1 + jD2   (>= 4*min(D1,D2) >= 132)
//   [5..9]   recurrence tap coeffs F_j (y = x'' + SUM F_j y[t-E_j])
//   [10..18] feedforward delays d_k, [19..27] feedforward coeffs n_k
__global__ __launch_bounds__(128) void coef_kernel(
    const float* __restrict__ da, const float* __restrict__ fa, const float* __restrict__ ra,
    const float* __restrict__ db, const float* __restrict__ fb, const float* __restrict__ rb,
    const float* __restrict__ dc, const float* __restrict__ fc, const float* __restrict__ rc,
    float* __restrict__ cws) {
  __shared__ float z[128];
  uint32_t keys[3][2];
#pragma unroll
  for (int q = 0; q < 3; ++q) {
    uint32_t x0 = 0u, x1 = (uint32_t)q;
    tf2x32(0u, 42u, x0, x1);
    keys[q][0] = x0; keys[q][1] = x1;
  }
  const float* dl[3] = {da, db, dc};
  const float* fg[3] = {fa, fb, fc};
  const float* rf[3] = {ra, rb, rc};
  const int Ls[3] = {85, 85, 8};
  const int md[3] = {40, 40, 32};
  const int i = threadIdx.x;
  for (int r = 0; r < 3; ++r) {
    const int L = Ls[r];
    z[i] = -3.4e38f;
    __syncthreads();
    if (i < L) {
      uint32_t x0 = 0u, x1 = (uint32_t)i;
      tf2x32(keys[r][0], keys[r][1], x0, x1);
      z[i] = dl[r][i] + gumbel_from_bits(x0 ^ x1);
    }
    __syncthreads();
    if (i == 0) {
      int p = 0; float best = z[0];
      for (int j = 1; j < L; ++j) { float v = z[j]; if (v > best) { best = v; p = j; } }
      const bool lowpass = (r == 2);
      float r0 = rf[r][0], r1 = rf[r][1];
      if (lowpass) { r0 = 1.f / (1.f + expf(-r0)); r1 = 1.f / (1.f + expf(-r1)); }
      else         { r0 = tanhf(r0);               r1 = tanhf(r1); }
      const float k1 = tanhf(r0), k2 = tanhf(r1);
      float a1 = k1 * (1.f - k2);
      const float a2 = fminf(fmaxf(k2, -0.999f), 0.999f);
      const float bnd = 0.999f - fabsf(a2);
      a1 = fminf(fmaxf(a1, -bnd), bnd);
      const float g = powf(1.f / (1.f + expf(-fg[r][0])), 0.45f);
      const int D1 = md[r] + p + 1;
      const int D2 = md[r] + ((p + 1) % L) + 1;
      const float C1 = a1 * g;           // y = x - C1 y[t-D1] - C2 y[t-D2]
      const float C2 = a2 * g;
      float* cw = cws + r * 32;
      // recurrence: 1 - P^4,  P = C1 z^-D1 + C2 z^-D2
      const float bin4[5] = {1.f, 4.f, 6.f, 4.f, 1.f};
      const float c1p[5] = {1.f, C1, C1*C1, C1*C1*C1, C1*C1*C1*C1};
      const float c2p[5] = {1.f, C2, C2*C2, C2*C2*C2, C2*C2*C2*C2};
      for (int j = 0; j < 5; ++j) {
        cw[j]     = (float)((4 - j) * D1 + j * D2);
        cw[5 + j] = bin4[j] * c1p[4 - j] * c2p[j];
      }
      // feedforward N = 1 - P + P^2 - P^3
      const int   fd[9] = {D1, D2, 2*D1, D1+D2, 2*D2, 3*D1, 2*D1+D2, D1+2*D2, 3*D2};
      const float fn[9] = {-C1, -C2, C1*C1, 2.f*C1*C2, C2*C2,
                           -C1*C1*C1, -3.f*C1*C1*C2, -3.f*C1*C2*C2, -C2*C2*C2};
      for (int k = 0; k < 9; ++k) {
        cw[10 + k] = (float)fd[k];
        cw[19 + k] = fn[k];
      }
    }
    __syncthreads();
  }
}

// ---------------- power-cycle-phase prefix sum (fp64 block scan) ----------------
__global__ __launch_bounds__(1024) void pcp_kernel(const float* __restrict__ f0,
                                                   float* __restrict__ pcp) {
  __shared__ double sm[1024];
  const int b = blockIdx.x;
  const int tid = threadIdx.x;
  const float* src = f0 + (size_t)b * T_;
  const int base = tid * 64;
  double loc = 0.0;
  for (int k = 0; k < 64; ++k) {
    loc += 6.283185307179586 * (double)src[base + k] / 48000.0;
  }
  sm[tid] = loc;
  __syncthreads();
  for (int off = 1; off < 1024; off <<= 1) {
    double v = (tid >= off) ? sm[tid - off] : 0.0;
    __syncthreads();
    sm[tid] += v;
    __syncthreads();
  }
  double run = (tid > 0) ? sm[tid - 1] : 0.0;
  float* dst = pcp + (size_t)b * T_;
  for (int k = 0; k < 64; ++k) {
    run += 6.283185307179586 * (double)src[base + k] / 48000.0;
    dst[base + k] = (float)(run * 0.5);
  }
}

// ---------------- harmonic synth + banks (memory-bound) ----------------
__global__ __launch_bounds__(256) void synth_kernel(
    const float* __restrict__ amps,   // (B,512,T)
    const float* __restrict__ fmg,    // (B,1,T)
    const float* __restrict__ cps,    // (B,16,T)
    const float* __restrict__ nba,    // (B,32,T)
    const float* __restrict__ nps,    // (B,2,T)
    const float* __restrict__ npg,    // (B,1,T)
    const float* __restrict__ fng,    // (B,1,T)
    const float* __restrict__ bands,  // (32,T)
    const float* __restrict__ pcp,    // (B,T) ws
    float* __restrict__ bank_a, float* __restrict__ bank_b) {
  const float TPF = 6.283185307179586f;
  const int gid = blockIdx.x * 256 + threadIdx.x;
  const int b = gid >> 15;
  const int t = (gid & 32767) * 2;
  const size_t bt = (size_t)b * T_ + t;
  const float p0 = pcp[bt], p1 = pcp[bt + 1];
  const float fm0 = fmg[bt], fm1 = fmg[bt + 1];

  float nse0 = 0.f, nse1 = 0.f;
  for (int n = 0; n < 32; ++n) {
    const float2 a = *(const float2*)(nba + ((size_t)b * 32 + n) * T_ + t);
    const float2 w = *(const float2*)(bands + (size_t)n * T_ + t);
    nse0 += a.x * w.x; nse1 += a.y * w.y;
  }

  const int order[8] = {0, 4, 3, 7, 5, 2, 6, 1};
  float ha0 = 0, ha1 = 0, hb0 = 0, hb1 = 0;
#pragma unroll
  for (int c = 0; c < 8; ++c) {
    const float ang = ((float)order[c] / 8.0f) * TPF;
    float s0 = p0 + ang; if (s0 >= TPF) s0 -= TPF;
    float s1 = p1 + ang; if (s1 >= TPF) s1 -= TPF;
    const float th0 = TPF * powf(s0 / TPF, fm0);
    const float th1 = TPF * powf(s1 / TPF, fm1);
    float sn0, cs0, sn1, cs1;
    sincosf(th0, &sn0, &cs0);
    sincosf(th1, &sn1, &cs1);
    float sp0 = 0.f, sc0 = sn0, sp1 = 0.f, sc1 = sn1;
    const float tc0 = 2.f * cs0, tc1 = 2.f * cs1;
    float acc0 = 0.f, acc1 = 0.f;
    const float* ap = amps + ((size_t)b * 512 + (size_t)c * 64) * T_ + t;
#pragma unroll 4
    for (int h = 0; h < 64; ++h) {
      const float2 a = *(const float2*)(ap + (size_t)h * T_);
      acc0 += a.x * sc0; acc1 += a.y * sc1;
      const float nx0 = tc0 * sc0 - sp0; sp0 = sc0; sc0 = nx0;
      const float nx1 = tc1 * sc1 - sp1; sp1 = sc1; sc1 = nx1;
    }
    const float2 al = *(const float2*)(cps + ((size_t)b * 16 + c) * T_ + t);
    const float2 be = *(const float2*)(cps + ((size_t)b * 16 + 8 + c) * T_ + t);
    const float env0 = (1.f - expf(-al.x * s0)) * expf(-be.x * s0);
    const float env1 = (1.f - expf(-al.y * s1)) * expf(-be.y * s1);
    const float hh0 = -acc0 * env0 * 10.f;
    const float hh1 = -acc1 * env1 * 10.f;
    if (c < 4) { ha0 += hh0; ha1 += hh1; } else { hb0 += hh0; hb1 += hh1; }
  }

  const float g0 = npg[bt], g1 = npg[bt + 1];
  const float fl0 = fng[bt], fl1 = fng[bt + 1];
  const float na0 = nps[(size_t)b * 2 * T_ + t],     na1 = nps[(size_t)b * 2 * T_ + t + 1];
  const float nb0 = nps[((size_t)b * 2 + 1) * T_ + t], nb1 = nps[((size_t)b * 2 + 1) * T_ + t + 1];
  float q0 = p0; if (q0 >= TPF) q0 -= TPF;
  float q1 = p1; if (q1 >= TPF) q1 -= TPF;
  const float ne0 = (1.f - expf(-na0 * q0)) * expf(-nb0 * q0);
  const float ne1 = (1.f - expf(-na1 * q1)) * expf(-nb1 * q1);
  const float com0 = nse0 * (ne0 * g0 + fl0 * 0.3f);
  const float com1 = nse1 * (ne1 * g1 + fl1 * 0.3f);
  const float K0 = nse0 * (g0 + fl0) * 0.7f;
  const float K1 = nse1 * (g1 + fl1) * 0.7f;
  *(float2*)(bank_a + bt) = make_float2(ha0 * (1.f + K0) + 4.f * com0,
                                        ha1 * (1.f + K1) + 4.f * com1);
  *(float2*)(bank_b + bt) = make_float2(hb0 * (1.f + K0) + 4.f * com0,
                                        hb1 * (1.f + K1) + 4.f * com1);
}

// ---------------- feedforward prep: x'' = x + SUM n_k x[t-d_k] --------------
__global__ __launch_bounds__(256) void prep_ab_kernel(
    const float* __restrict__ BA, const float* __restrict__ BB,
    const float* __restrict__ CW, float* __restrict__ XA, float* __restrict__ XB) {
  const int idx = blockIdx.x * 256 + threadIdx.x;   // 0..262143
  const int t = idx & (T_ - 1);
  const int s = idx >> 16;                           // 0..3
  const int r = s >> 1, b = s & 1;
  const float* xin = (r == 0 ? BA : BB) + (size_t)b * T_;
  float* xout = (r == 0 ? XA : XB) + (size_t)b * T_;
  const float* cw = CW + r * 32;
  float acc = xin[t];
#pragma unroll
  for (int k = 0; k < 9; ++k) {
    const int d = (int)cw[10 + k];
    const float n = cw[19 + k];
    const int tc = t - d;
    const float u = xin[tc >= 0 ? tc : 0];
    acc += (tc >= 0) ? n * u : 0.f;
  }
  xout[t] = acc;
}

__global__ __launch_bounds__(256) void prep_c_kernel(
    const float* __restrict__ RA, const float* __restrict__ RB,
    const float* __restrict__ CW, float* __restrict__ XC) {
  const int idx = blockIdx.x * 256 + threadIdx.x;   // 0..131071
  const int t = idx & (T_ - 1);
  const int b = idx >> 16;
  const float* ya = RA + (size_t)b * T_;
  const float* yb = RB + (size_t)b * T_;
  const float* cw = CW + 64;
  float acc = ya[t] + yb[t];
#pragma unroll
  for (int k = 0; k < 9; ++k) {
    const int d = (int)cw[10 + k];
    const float n = cw[19 + k];
    const int tc = t - d;
    const float u = ya[tc >= 0 ? tc : 0] + yb[tc >= 0 ? tc : 0];
    acc += (tc >= 0) ? n * u : 0.f;
  }
  XC[idx] = acc;
}

// ---------------- resonator scan: delay-quadrupled 5-tap recurrence ----------
// One wave per filter. C = 64 lanes, 1024 steps. All tap delays E >= 132 =
// 2*64+4, so taps for step s+2 are final at step s (slot t+128-E <= t-4;
// same-wave DS is in-order, same-step writes visible). TWO-step-ahead tap
// prefetch (two named register sets, unroll-2) removes the exposed LDS
// issue-to-use latency that the round-9 one-step prefetch paid (~120 cy vs
// ~70 cy/step budget, single wave = no TLP to hide it). xv gets 2-step slack
// within the staged buffer; first two xv of each phase are read right after
// the vmcnt drain (amortized ~8 cy/step). Steps are now issue-bound.
__device__ __forceinline__ void gld16(const float* g, float* l) {
  __builtin_amdgcn_global_load_lds((const __attribute__((address_space(1))) void*)g,
                                   (__attribute__((address_space(3))) void*)l, 16, 0, 0);
}

__device__ __forceinline__ void poly_scan(const float* __restrict__ x,
                                          float* __restrict__ y,
                                          const float* __restrict__ cf,
                                          float* __restrict__ sm) {
  const int o = threadIdx.x & 63;
  const int e0 = (int)cf[0], e1 = (int)cf[1], e2 = (int)cf[2],
            e3 = (int)cf[3], e4 = (int)cf[4];
  const float fc0 = cf[5], fc1 = cf[6], fc2 = cf[7], fc3 = cf[8], fc4 = cf[9];
  float* ring = sm;          // 1024 floats
  float* st   = sm + 1024;   // 2 x 1024 floats staging

  // zero ring (in-order DS: zeros visible to the priming reads below)
#pragma unroll
  for (int i = 0; i < 16; ++i) ring[o + i * 64] = 0.f;

  // stage segment 0 -> buffer 0
  {
    const float* g = x + (o << 2);
    gld16(g, st); gld16(g + 256, st + 256);
    gld16(g + 512, st + 512); gld16(g + 768, st + 768);
  }

  // prime taps for step 0 (t=o) and step 1 (t=o+64); both read pre-zeroed
  // slots that are not rewritten before use (wrapped indices >= 524).
  float a0 = ring[(o - e0) & 1023];
  float a1v = ring[(o - e1) & 1023];
  float a2v = ring[(o - e2) & 1023];
  float a3v = ring[(o - e3) & 1023];
  float a4v = ring[(o - e4) & 1023];
  float b0 = ring[(o + 64 - e0) & 1023];
  float b1v = ring[(o + 64 - e1) & 1023];
  float b2v = ring[(o + 64 - e2) & 1023];
  float b3v = ring[(o + 64 - e3) & 1023];
  float b4v = ring[(o + 64 - e4) & 1023];

  int t = o;
  for (int ph = 0; ph < 64; ++ph) {
    const int q = ph & 1;
    // buffer q's DMA was issued a full phase ago -> cheap drain.
    asm volatile("s_waitcnt vmcnt(0)" ::: "memory");
    if (ph < 63) {   // uniform branch: issue next segment into the other buffer
      const float* g = x + (ph + 1) * 1024 + (o << 2);
      float* l = st + (q ^ 1) * 1024;
      gld16(g, l); gld16(g + 256, l + 256);
      gld16(g + 512, l + 512); gld16(g + 768, l + 768);
    }
    const float* bq = st + q * 1024;
    float xv0 = bq[o];            // steps 0,1 of this phase (post-drain, valid)
    float xv1 = bq[64 + o];
#pragma unroll
    for (int l = 0; l < 16; l += 2) {
      {  // even step: uses tap set A, prefetches A for step+2
        const float s01 = fmaf(fc0, a0, fc1 * a1v);
        const float s23 = fmaf(fc2, a2v, fc3 * a3v);
        const float yv = xv0 + (s01 + fmaf(fc4, a4v, s23));
        ring[t & 1023] = yv;
        y[t] = yv;
        a0  = ring[(t + 128 - e0) & 1023];
        a1v = ring[(t + 128 - e1) & 1023];
        a2v = ring[(t + 128 - e2) & 1023];
        a3v = ring[(t + 128 - e3) & 1023];
        a4v = ring[(t + 128 - e4) & 1023];
        if (l + 2 < 16) xv0 = bq[(l + 2) * 64 + o];
        t += 64;
      }
      {  // odd step: uses tap set B, prefetches B for step+2
        const float s01 = fmaf(fc0, b0, fc1 * b1v);
        const float s23 = fmaf(fc2, b2v, fc3 * b3v);
        const float yv = xv1 + (s01 + fmaf(fc4, b4v, s23));
        ring[t & 1023] = yv;
        y[t] = yv;
        b0  = ring[(t + 128 - e0) & 1023];
        b1v = ring[(t + 128 - e1) & 1023];
        b2v = ring[(t + 128 - e2) & 1023];
        b3v = ring[(t + 128 - e3) & 1023];
        b4v = ring[(t + 128 - e4) & 1023];
        if (l + 3 < 16) xv1 = bq[(l + 3) * 64 + o];
        t += 64;
      }
    }
  }
}

__global__ __launch_bounds__(64) void res_ab_kernel(
    const float* __restrict__ XA, const float* __restrict__ XB,
    float* __restrict__ RA, float* __restrict__ RB, const float* __restrict__ CW) {
  __shared__ float sm[3072];
  const int r = blockIdx.x >> 1;
  const int b = blockIdx.x & 1;
  poly_scan((r == 0 ? XA : XB) + (size_t)b * T_,
            (r == 0 ? RA : RB) + (size_t)b * T_, CW + r * 32, sm);
}

__global__ __launch_bounds__(64) void res_c_kernel(
    const float* __restrict__ XC, float* __restrict__ out,
    const float* __restrict__ CW) {
  __shared__ float sm[3072];
  poly_scan(XC + (size_t)blockIdx.x * T_, out + (size_t)blockIdx.x * T_,
            CW + 64, sm);
}

// ---------------- launch ----------------
extern "C" void kernel_launch(void* const* d_in, const int* in_sizes, int n_in,
                              void* d_out, int out_size, void* d_ws, size_t ws_size,
                              hipStream_t stream) {
  const float* f0    = (const float*)d_in[0];
  const float* amps  = (const float*)d_in[1];
  const float* fmg   = (const float*)d_in[2];
  const float* cps   = (const float*)d_in[4];
  const float* nba   = (const float*)d_in[5];
  const float* nps   = (const float*)d_in[6];
  const float* npg   = (const float*)d_in[7];
  const float* fng   = (const float*)d_in[8];
  const float* bands = (const float*)d_in[9];
  const float* da  = (const float*)d_in[10];
  const float* fga = (const float*)d_in[11];
  const float* ra  = (const float*)d_in[12];
  const float* db  = (const float*)d_in[13];
  const float* fgb = (const float*)d_in[14];
  const float* rb  = (const float*)d_in[15];
  const float* dc  = (const float*)d_in[16];
  const float* fgc = (const float*)d_in[17];
  const float* rc  = (const float*)d_in[18];
  float* out = (float*)d_out;
  float* ws  = (float*)d_ws;

  // slots of 131072 floats (B*T):
  float* S0 = ws;              // pcp  -> later XA (x''_a)
  float* S1 = ws + 131072;     // bank_a -> later RA (res_a)
  float* S2 = ws + 262144;     // bank_b -> later RB (res_b)
  float* S3 = ws + 393216;     // XB (x''_b) -> later XC (x''_c)
  float* CW = ws + 524288;     // coefficients (96 floats)

  pcp_kernel<<<2, 1024, 0, stream>>>(f0, S0);
  coef_kernel<<<1, 128, 0, stream>>>(da, fga, ra, db, fgb, rb, dc, fgc, rc, CW);
  synth_kernel<<<256, 256, 0, stream>>>(amps, fmg, cps, nba, nps, npg, fng, bands,
                                        S0, S1, S2);
  // feedforward for banks: XA<-S0 (pcp dead), XB<-S3; reads banks S1,S2
  prep_ab_kernel<<<1024, 256, 0, stream>>>(S1, S2, CW, S0, S3);
  // scans: RA->S1 (bank_a dead), RB->S2 (bank_b dead); reads XA=S0, XB=S3
  res_ab_kernel<<<4, 64, 0, stream>>>(S0, S3, S1, S2, CW);
  // feedforward for c: XC<-S3 (XB dead); reads RA=S1, RB=S2
  prep_c_kernel<<<512, 256, 0, stream>>>(S1, S2, CW, S3);
  res_c_kernel<<<2, 64, 0, stream>>>(S3, out, CW);
}

// Round 11
// 259.980 us; speedup vs baseline: 3.5599x; 1.1446x over previous
//
#include <hip/hip_runtime.h>
#include <cstdint>
#include <cstddef>

#define T_ 65536

// ---------------- threefry2x32 (bit-exact vs JAX) ----------------
__device__ __forceinline__ void tf2x32(uint32_t k0, uint32_t k1,
                                       uint32_t& x0, uint32_t& x1) {
  const uint32_t ks[3] = {k0, k1, k0 ^ k1 ^ 0x1BD11BDAu};
  const int R[8] = {13, 15, 26, 6, 17, 29, 16, 24};
  x0 += ks[0]; x1 += ks[1];
#pragma unroll
  for (int i = 0; i < 5; ++i) {
#pragma unroll
    for (int j = 0; j < 4; ++j) {
      const int r = R[(i & 1) * 4 + j];
      x0 += x1;
      x1 = (x1 << r) | (x1 >> (32 - r));
      x1 ^= x0;
    }
    x0 += ks[(i + 1) % 3];
    x1 += ks[(i + 2) % 3] + (uint32_t)(i + 1);
  }
}

__device__ __forceinline__ float gumbel_from_bits(uint32_t b) {
  float u = __uint_as_float((b >> 9) | 0x3f800000u) - 1.0f;
  u = fmaxf(u, 1.17549435e-38f);
  return -logf(-logf(u));
}

// ---------------- coefficient setup (1 block) ----------------
// JAX threefry_partitionable path (default since 0.4.36).
// Per resonator r (stride 32 floats in cws):
//   [0..4]   recurrence tap delays E_j = (4-j)D1 + jD2   (>= 4*min(D1,D2) >= 132)
//   [5..9]   recurrence tap coeffs F_j (y = x'' + SUM F_j y[t-E_j])
//   [10..18] feedforward delays d_k, [19..27] feedforward coeffs n_k
__global__ __launch_bounds__(128) void coef_kernel(
    const float* __restrict__ da, const float* __restrict__ fa, const float* __restrict__ ra,
    const float* __restrict__ db, const float* __restrict__ fb, const float* __restrict__ rb,
    const float* __restrict__ dc, const float* __restrict__ fc, const float* __restrict__ rc,
    float* __restrict__ cws) {
  __shared__ float z[128];
  uint32_t keys[3][2];
#pragma unroll
  for (int q = 0; q < 3; ++q) {
    uint32_t x0 = 0u, x1 = (uint32_t)q;
    tf2x32(0u, 42u, x0, x1);
    keys[q][0] = x0; keys[q][1] = x1;
  }
  const float* dl[3] = {da, db, dc};
  const float* fg[3] = {fa, fb, fc};
  const float* rf[3] = {ra, rb, rc};
  const int Ls[3] = {85, 85, 8};
  const int md[3] = {40, 40, 32};
  const int i = threadIdx.x;
  for (int r = 0; r < 3; ++r) {
    const int L = Ls[r];
    z[i] = -3.4e38f;
    __syncthreads();
    if (i < L) {
      uint32_t x0 = 0u, x1 = (uint32_t)i;
      tf2x32(keys[r][0], keys[r][1], x0, x1);
      z[i] = dl[r][i] + gumbel_from_bits(x0 ^ x1);
    }
    __syncthreads();
    if (i == 0) {
      int p = 0; float best = z[0];
      for (int j = 1; j < L; ++j) { float v = z[j]; if (v > best) { best = v; p = j; } }
      const bool lowpass = (r == 2);
      float r0 = rf[r][0], r1 = rf[r][1];
      if (lowpass) { r0 = 1.f / (1.f + expf(-r0)); r1 = 1.f / (1.f + expf(-r1)); }
      else         { r0 = tanhf(r0);               r1 = tanhf(r1); }
      const float k1 = tanhf(r0), k2 = tanhf(r1);
      float a1 = k1 * (1.f - k2);
      const float a2 = fminf(fmaxf(k2, -0.999f), 0.999f);
      const float bnd = 0.999f - fabsf(a2);
      a1 = fminf(fmaxf(a1, -bnd), bnd);
      const float g = powf(1.f / (1.f + expf(-fg[r][0])), 0.45f);
      const int D1 = md[r] + p + 1;
      const int D2 = md[r] + ((p + 1) % L) + 1;
      const float C1 = a1 * g;           // y = x - C1 y[t-D1] - C2 y[t-D2]
      const float C2 = a2 * g;
      float* cw = cws + r * 32;
      // recurrence: 1 - P^4,  P = C1 z^-D1 + C2 z^-D2
      const float bin4[5] = {1.f, 4.f, 6.f, 4.f, 1.f};
      const float c1p[5] = {1.f, C1, C1*C1, C1*C1*C1, C1*C1*C1*C1};
      const float c2p[5] = {1.f, C2, C2*C2, C2*C2*C2, C2*C2*C2*C2};
      for (int j = 0; j < 5; ++j) {
        cw[j]     = (float)((4 - j) * D1 + j * D2);
        cw[5 + j] = bin4[j] * c1p[4 - j] * c2p[j];
      }
      // feedforward N = 1 - P + P^2 - P^3
      const int   fd[9] = {D1, D2, 2*D1, D1+D2, 2*D2, 3*D1, 2*D1+D2, D1+2*D2, 3*D2};
      const float fn[9] = {-C1, -C2, C1*C1, 2.f*C1*C2, C2*C2,
                           -C1*C1*C1, -3.f*C1*C1*C2, -3.f*C1*C2*C2, -C2*C2*C2};
      for (int k = 0; k < 9; ++k) {
        cw[10 + k] = (float)fd[k];
        cw[19 + k] = fn[k];
      }
    }
    __syncthreads();
  }
}

// ---------------- power-cycle-phase prefix sum (fp64 block scan) ----------------
__global__ __launch_bounds__(1024) void pcp_kernel(const float* __restrict__ f0,
                                                   float* __restrict__ pcp) {
  __shared__ double sm[1024];
  const int b = blockIdx.x;
  const int tid = threadIdx.x;
  const float* src = f0 + (size_t)b * T_;
  const int base = tid * 64;
  double loc = 0.0;
  for (int k = 0; k < 64; ++k) {
    loc += 6.283185307179586 * (double)src[base + k] / 48000.0;
  }
  sm[tid] = loc;
  __syncthreads();
  for (int off = 1; off < 1024; off <<= 1) {
    double v = (tid >= off) ? sm[tid - off] : 0.0;
    __syncthreads();
    sm[tid] += v;
    __syncthreads();
  }
  double run = (tid > 0) ? sm[tid - 1] : 0.0;
  float* dst = pcp + (size_t)b * T_;
  for (int k = 0; k < 64; ++k) {
    run += 6.283185307179586 * (double)src[base + k] / 48000.0;
    dst[base + k] = (float)(run * 0.5);
  }
}

// ---------------- harmonic synth + banks (memory-bound) ----------------
// Round-11 restructure: block = 4 cylinder-groups x 64 lanes covering 128
// samples (2 per lane, float2 loads). Each group computes 2 cylinders + 8 of
// the 32 noise bands; partials meet in LDS (one barrier); group 0 applies the
// noise envelopes/turbulence and writes both banks. Grid 1024 blocks -> 4096
// waves (16/CU) vs the old 1024 waves (4/CU): 4x the latency hiding and 4x
// shorter serial Chebyshev chains at identical HBM traffic.
__global__ __launch_bounds__(256) void synth_kernel(
    const float* __restrict__ amps,   // (B,512,T)
    const float* __restrict__ fmg,    // (B,1,T)
    const float* __restrict__ cps,    // (B,16,T)
    const float* __restrict__ nba,    // (B,32,T)
    const float* __restrict__ nps,    // (B,2,T)
    const float* __restrict__ npg,    // (B,1,T)
    const float* __restrict__ fng,    // (B,1,T)
    const float* __restrict__ bands,  // (32,T)
    const float* __restrict__ pcp,    // (B,T) ws
    float* __restrict__ bank_a, float* __restrict__ bank_b) {
  const float TPF = 6.283185307179586f;
  const int lane = threadIdx.x & 63;
  const int g    = threadIdx.x >> 6;          // cylinder group 0..3
  const int blk  = blockIdx.x;                // 0..1023
  const int b    = blk >> 9;                  // 512 blocks per batch
  const int t    = (blk & 511) * 128 + lane * 2;
  const size_t bt = (size_t)b * T_ + t;

  __shared__ float2 redN[4][64];
  __shared__ float2 redH[4][64];

  const float p0 = pcp[bt], p1 = pcp[bt + 1];
  const float fm0 = fmg[bt], fm1 = fmg[bt + 1];

  // noise partial: bands 8g .. 8g+7
  float nse0 = 0.f, nse1 = 0.f;
#pragma unroll
  for (int j = 0; j < 8; ++j) {
    const int n = g * 8 + j;
    const float2 a = *(const float2*)(nba + ((size_t)b * 32 + n) * T_ + t);
    const float2 w = *(const float2*)(bands + (size_t)n * T_ + t);
    nse0 += a.x * w.x; nse1 += a.y * w.y;
  }
  redN[g][lane] = make_float2(nse0, nse1);

  // harmonics partial: cylinders 2g, 2g+1
  const int order[8] = {0, 4, 3, 7, 5, 2, 6, 1};
  float hp0 = 0.f, hp1 = 0.f;
#pragma unroll
  for (int cc = 0; cc < 2; ++cc) {
    const int c = 2 * g + cc;
    const float ang = ((float)order[c] / 8.0f) * TPF;
    float s0 = p0 + ang; if (s0 >= TPF) s0 -= TPF;
    float s1 = p1 + ang; if (s1 >= TPF) s1 -= TPF;
    const float th0 = TPF * powf(s0 / TPF, fm0);
    const float th1 = TPF * powf(s1 / TPF, fm1);
    float sn0, cs0, sn1, cs1;
    sincosf(th0, &sn0, &cs0);
    sincosf(th1, &sn1, &cs1);
    float sp0 = 0.f, sc0 = sn0, sp1 = 0.f, sc1 = sn1;
    const float tc0 = 2.f * cs0, tc1 = 2.f * cs1;
    float acc0 = 0.f, acc1 = 0.f;
    const float* ap = amps + ((size_t)b * 512 + (size_t)c * 64) * T_ + t;
#pragma unroll 4
    for (int h = 0; h < 64; ++h) {
      const float2 a = *(const float2*)(ap + (size_t)h * T_);
      acc0 += a.x * sc0; acc1 += a.y * sc1;
      const float nx0 = tc0 * sc0 - sp0; sp0 = sc0; sc0 = nx0;
      const float nx1 = tc1 * sc1 - sp1; sp1 = sc1; sc1 = nx1;
    }
    const float2 al = *(const float2*)(cps + ((size_t)b * 16 + c) * T_ + t);
    const float2 be = *(const float2*)(cps + ((size_t)b * 16 + 8 + c) * T_ + t);
    const float env0 = (1.f - expf(-al.x * s0)) * expf(-be.x * s0);
    const float env1 = (1.f - expf(-al.y * s1)) * expf(-be.y * s1);
    hp0 += -acc0 * env0 * 10.f;
    hp1 += -acc1 * env1 * 10.f;
  }
  redH[g][lane] = make_float2(hp0, hp1);
  __syncthreads();

  if (g == 0) {
    const float2 n0 = redN[0][lane], n1 = redN[1][lane],
                 n2 = redN[2][lane], n3 = redN[3][lane];
    const float nseA = n0.x + n1.x + n2.x + n3.x;
    const float nseB = n0.y + n1.y + n2.y + n3.y;
    const float2 h0 = redH[0][lane], h1 = redH[1][lane],
                 h2 = redH[2][lane], h3 = redH[3][lane];
    const float ha0 = h0.x + h1.x, ha1 = h0.y + h1.y;
    const float hb0 = h2.x + h3.x, hb1 = h2.y + h3.y;

    const float g0 = npg[bt], g1 = npg[bt + 1];
    const float fl0 = fng[bt], fl1 = fng[bt + 1];
    const float na0 = nps[(size_t)b * 2 * T_ + t],       na1 = nps[(size_t)b * 2 * T_ + t + 1];
    const float nb0 = nps[((size_t)b * 2 + 1) * T_ + t], nb1 = nps[((size_t)b * 2 + 1) * T_ + t + 1];
    float q0 = p0; if (q0 >= TPF) q0 -= TPF;
    float q1 = p1; if (q1 >= TPF) q1 -= TPF;
    const float ne0 = (1.f - expf(-na0 * q0)) * expf(-nb0 * q0);
    const float ne1 = (1.f - expf(-na1 * q1)) * expf(-nb1 * q1);
    const float com0 = nseA * (ne0 * g0 + fl0 * 0.3f);
    const float com1 = nseB * (ne1 * g1 + fl1 * 0.3f);
    const float K0 = nseA * (g0 + fl0) * 0.7f;
    const float K1 = nseB * (g1 + fl1) * 0.7f;
    *(float2*)(bank_a + bt) = make_float2(ha0 * (1.f + K0) + 4.f * com0,
                                          ha1 * (1.f + K1) + 4.f * com1);
    *(float2*)(bank_b + bt) = make_float2(hb0 * (1.f + K0) + 4.f * com0,
                                          hb1 * (1.f + K1) + 4.f * com1);
  }
}

// ---------------- feedforward prep: x'' = x + SUM n_k x[t-d_k] --------------
__global__ __launch_bounds__(256) void prep_ab_kernel(
    const float* __restrict__ BA, const float* __restrict__ BB,
    const float* __restrict__ CW, float* __restrict__ XA, float* __restrict__ XB) {
  const int idx = blockIdx.x * 256 + threadIdx.x;   // 0..262143
  const int t = idx & (T_ - 1);
  const int s = idx >> 16;                           // 0..3
  const int r = s >> 1, b = s & 1;
  const float* xin = (r == 0 ? BA : BB) + (size_t)b * T_;
  float* xout = (r == 0 ? XA : XB) + (size_t)b * T_;
  const float* cw = CW + r * 32;
  float acc = xin[t];
#pragma unroll
  for (int k = 0; k < 9; ++k) {
    const int d = (int)cw[10 + k];
    const float n = cw[19 + k];
    const int tc = t - d;
    const float u = xin[tc >= 0 ? tc : 0];
    acc += (tc >= 0) ? n * u : 0.f;
  }
  xout[t] = acc;
}

__global__ __launch_bounds__(256) void prep_c_kernel(
    const float* __restrict__ RA, const float* __restrict__ RB,
    const float* __restrict__ CW, float* __restrict__ XC) {
  const int idx = blockIdx.x * 256 + threadIdx.x;   // 0..131071
  const int t = idx & (T_ - 1);
  const int b = idx >> 16;
  const float* ya = RA + (size_t)b * T_;
  const float* yb = RB + (size_t)b * T_;
  const float* cw = CW + 64;
  float acc = ya[t] + yb[t];
#pragma unroll
  for (int k = 0; k < 9; ++k) {
    const int d = (int)cw[10 + k];
    const float n = cw[19 + k];
    const int tc = t - d;
    const float u = ya[tc >= 0 ? tc : 0] + yb[tc >= 0 ? tc : 0];
    acc += (tc >= 0) ? n * u : 0.f;
  }
  XC[idx] = acc;
}

// ---------------- resonator scan: delay-quadrupled 5-tap recurrence ----------
// One wave per filter. 1024 steps, two-step-ahead tap prefetch (see round 10).
__device__ __forceinline__ void gld16(const float* g, float* l) {
  __builtin_amdgcn_global_load_lds((const __attribute__((address_space(1))) void*)g,
                                   (__attribute__((address_space(3))) void*)l, 16, 0, 0);
}

__device__ __forceinline__ void poly_scan(const float* __restrict__ x,
                                          float* __restrict__ y,
                                          const float* __restrict__ cf,
                                          float* __restrict__ sm) {
  const int o = threadIdx.x & 63;
  const int e0 = (int)cf[0], e1 = (int)cf[1], e2 = (int)cf[2],
            e3 = (int)cf[3], e4 = (int)cf[4];
  const float fc0 = cf[5], fc1 = cf[6], fc2 = cf[7], fc3 = cf[8], fc4 = cf[9];
  float* ring = sm;          // 1024 floats
  float* st   = sm + 1024;   // 2 x 1024 floats staging

#pragma unroll
  for (int i = 0; i < 16; ++i) ring[o + i * 64] = 0.f;

  {
    const float* g = x + (o << 2);
    gld16(g, st); gld16(g + 256, st + 256);
    gld16(g + 512, st + 512); gld16(g + 768, st + 768);
  }

  float a0 = ring[(o - e0) & 1023];
  float a1v = ring[(o - e1) & 1023];
  float a2v = ring[(o - e2) & 1023];
  float a3v = ring[(o - e3) & 1023];
  float a4v = ring[(o - e4) & 1023];
  float b0 = ring[(o + 64 - e0) & 1023];
  float b1v = ring[(o + 64 - e1) & 1023];
  float b2v = ring[(o + 64 - e2) & 1023];
  float b3v = ring[(o + 64 - e3) & 1023];
  float b4v = ring[(o + 64 - e4) & 1023];

  int t = o;
  for (int ph = 0; ph < 64; ++ph) {
    const int q = ph & 1;
    asm volatile("s_waitcnt vmcnt(0)" ::: "memory");
    if (ph < 63) {
      const float* g = x + (ph + 1) * 1024 + (o << 2);
      float* l = st + (q ^ 1) * 1024;
      gld16(g, l); gld16(g + 256, l + 256);
      gld16(g + 512, l + 512); gld16(g + 768, l + 768);
    }
    const float* bq = st + q * 1024;
    float xv0 = bq[o];
    float xv1 = bq[64 + o];
#pragma unroll
    for (int l = 0; l < 16; l += 2) {
      {
        const float s01 = fmaf(fc0, a0, fc1 * a1v);
        const float s23 = fmaf(fc2, a2v, fc3 * a3v);
        const float yv = xv0 + (s01 + fmaf(fc4, a4v, s23));
        ring[t & 1023] = yv;
        y[t] = yv;
        a0  = ring[(t + 128 - e0) & 1023];
        a1v = ring[(t + 128 - e1) & 1023];
        a2v = ring[(t + 128 - e2) & 1023];
        a3v = ring[(t + 128 - e3) & 1023];
        a4v = ring[(t + 128 - e4) & 1023];
        if (l + 2 < 16) xv0 = bq[(l + 2) * 64 + o];
        t += 64;
      }
      {
        const float s01 = fmaf(fc0, b0, fc1 * b1v);
        const float s23 = fmaf(fc2, b2v, fc3 * b3v);
        const float yv = xv1 + (s01 + fmaf(fc4, b4v, s23));
        ring[t & 1023] = yv;
        y[t] = yv;
        b0  = ring[(t + 128 - e0) & 1023];
        b1v = ring[(t + 128 - e1) & 1023];
        b2v = ring[(t + 128 - e2) & 1023];
        b3v = ring[(t + 128 - e3) & 1023];
        b4v = ring[(t + 128 - e4) & 1023];
        if (l + 3 < 16) xv1 = bq[(l + 3) * 64 + o];
        t += 64;
      }
    }
  }
}

__global__ __launch_bounds__(64) void res_ab_kernel(
    const float* __restrict__ XA, const float* __restrict__ XB,
    float* __restrict__ RA, float* __restrict__ RB, const float* __restrict__ CW) {
  __shared__ float sm[3072];
  const int r = blockIdx.x >> 1;
  const int b = blockIdx.x & 1;
  poly_scan((r == 0 ? XA : XB) + (size_t)b * T_,
            (r == 0 ? RA : RB) + (size_t)b * T_, CW + r * 32, sm);
}

__global__ __launch_bounds__(64) void res_c_kernel(
    const float* __restrict__ XC, float* __restrict__ out,
    const float* __restrict__ CW) {
  __shared__ float sm[3072];
  poly_scan(XC + (size_t)blockIdx.x * T_, out + (size_t)blockIdx.x * T_,
            CW + 64, sm);
}

// ---------------- launch ----------------
extern "C" void kernel_launch(void* const* d_in, const int* in_sizes, int n_in,
                              void* d_out, int out_size, void* d_ws, size_t ws_size,
                              hipStream_t stream) {
  const float* f0    = (const float*)d_in[0];
  const float* amps  = (const float*)d_in[1];
  const float* fmg   = (const float*)d_in[2];
  const float* cps   = (const float*)d_in[4];
  const float* nba   = (const float*)d_in[5];
  const float* nps   = (const float*)d_in[6];
  const float* npg   = (const float*)d_in[7];
  const float* fng   = (const float*)d_in[8];
  const float* bands = (const float*)d_in[9];
  const float* da  = (const float*)d_in[10];
  const float* fga = (const float*)d_in[11];
  const float* ra  = (const float*)d_in[12];
  const float* db  = (const float*)d_in[13];
  const float* fgb = (const float*)d_in[14];
  const float* rb  = (const float*)d_in[15];
  const float* dc  = (const float*)d_in[16];
  const float* fgc = (const float*)d_in[17];
  const float* rc  = (const float*)d_in[18];
  float* out = (float*)d_out;
  float* ws  = (float*)d_ws;

  // slots of 131072 floats (B*T):
  float* S0 = ws;              // pcp  -> later XA (x''_a)
  float* S1 = ws + 131072;     // bank_a -> later RA (res_a)
  float* S2 = ws + 262144;     // bank_b -> later RB (res_b)
  float* S3 = ws + 393216;     // XB (x''_b) -> later XC (x''_c)
  float* CW = ws + 524288;     // coefficients (96 floats)

  pcp_kernel<<<2, 1024, 0, stream>>>(f0, S0);
  coef_kernel<<<1, 128, 0, stream>>>(da, fga, ra, db, fgb, rb, dc, fgc, rc, CW);
  synth_kernel<<<1024, 256, 0, stream>>>(amps, fmg, cps, nba, nps, npg, fng, bands,
                                         S0, S1, S2);
  // feedforward for banks: XA<-S0 (pcp dead), XB<-S3; reads banks S1,S2
  prep_ab_kernel<<<1024, 256, 0, stream>>>(S1, S2, CW, S0, S3);
  // scans: RA->S1 (bank_a dead), RB->S2 (bank_b dead); reads XA=S0, XB=S3
  res_ab_kernel<<<4, 64, 0, stream>>>(S0, S3, S1, S2, CW);
  // feedforward for c: XC<-S3 (XB dead); reads RA=S1, RB=S2
  prep_c_kernel<<<512, 256, 0, stream>>>(S1, S2, CW, S3);
  res_c_kernel<<<2, 64, 0, stream>>>(S3, out, CW);
}

// Round 12
// 254.786 us; speedup vs baseline: 3.6325x; 1.0204x over previous
//
#include <hip/hip_runtime.h>
#include <cstdint>
#include <cstddef>

#define T_ 65536

// ---------------- threefry2x32 (bit-exact vs JAX) ----------------
__device__ __forceinline__ void tf2x32(uint32_t k0, uint32_t k1,
                                       uint32_t& x0, uint32_t& x1) {
  const uint32_t ks[3] = {k0, k1, k0 ^ k1 ^ 0x1BD11BDAu};
  const int R[8] = {13, 15, 26, 6, 17, 29, 16, 24};
  x0 += ks[0]; x1 += ks[1];
#pragma unroll
  for (int i = 0; i < 5; ++i) {
#pragma unroll
    for (int j = 0; j < 4; ++j) {
      const int r = R[(i & 1) * 4 + j];
      x0 += x1;
      x1 = (x1 << r) | (x1 >> (32 - r));
      x1 ^= x0;
    }
    x0 += ks[(i + 1) % 3];
    x1 += ks[(i + 2) % 3] + (uint32_t)(i + 1);
  }
}

__device__ __forceinline__ float gumbel_from_bits(uint32_t b) {
  float u = __uint_as_float((b >> 9) | 0x3f800000u) - 1.0f;
  u = fmaxf(u, 1.17549435e-38f);
  return -logf(-logf(u));
}

// ---------------- fused pcp prefix-scan (blocks 0,1) + coef setup (block 2) --
// coef layout per resonator r (stride 32 floats in cws):
//   [0..4] recurrence delays E_j=(4-j)D1+jD2 (>=132); [5..9] coeffs F_j
//   [10..18] feedforward delays d_k; [19..27] feedforward coeffs n_k
__global__ __launch_bounds__(1024) void pcp_coef_kernel(
    const float* __restrict__ f0, float* __restrict__ pcp,
    const float* __restrict__ da, const float* __restrict__ fa, const float* __restrict__ ra,
    const float* __restrict__ db, const float* __restrict__ fb, const float* __restrict__ rb,
    const float* __restrict__ dc, const float* __restrict__ fc, const float* __restrict__ rc,
    float* __restrict__ cws) {
  __shared__ double sm[1024];
  __shared__ float z[128];
  if (blockIdx.x < 2) {
    const int b = blockIdx.x;
    const int tid = threadIdx.x;
    const float* src = f0 + (size_t)b * T_;
    const int base = tid * 64;
    double loc = 0.0;
    for (int k = 0; k < 64; ++k) {
      loc += 6.283185307179586 * (double)src[base + k] / 48000.0;
    }
    sm[tid] = loc;
    __syncthreads();
    for (int off = 1; off < 1024; off <<= 1) {
      double v = (tid >= off) ? sm[tid - off] : 0.0;
      __syncthreads();
      sm[tid] += v;
      __syncthreads();
    }
    double run = (tid > 0) ? sm[tid - 1] : 0.0;
    float* dst = pcp + (size_t)b * T_;
    for (int k = 0; k < 64; ++k) {
      run += 6.283185307179586 * (double)src[base + k] / 48000.0;
      dst[base + k] = (float)(run * 0.5);
    }
  } else {
    uint32_t keys[3][2];
#pragma unroll
    for (int q = 0; q < 3; ++q) {
      uint32_t x0 = 0u, x1 = (uint32_t)q;
      tf2x32(0u, 42u, x0, x1);
      keys[q][0] = x0; keys[q][1] = x1;
    }
    const float* dl[3] = {da, db, dc};
    const float* fg[3] = {fa, fb, fc};
    const float* rf[3] = {ra, rb, rc};
    const int Ls[3] = {85, 85, 8};
    const int md[3] = {40, 40, 32};
    const int i = threadIdx.x;
    for (int r = 0; r < 3; ++r) {
      const int L = Ls[r];
      if (i < 128) z[i] = -3.4e38f;
      __syncthreads();
      if (i < L) {
        uint32_t x0 = 0u, x1 = (uint32_t)i;
        tf2x32(keys[r][0], keys[r][1], x0, x1);
        z[i] = dl[r][i] + gumbel_from_bits(x0 ^ x1);
      }
      __syncthreads();
      if (i == 0) {
        int p = 0; float best = z[0];
        for (int j = 1; j < L; ++j) { float v = z[j]; if (v > best) { best = v; p = j; } }
        const bool lowpass = (r == 2);
        float r0 = rf[r][0], r1 = rf[r][1];
        if (lowpass) { r0 = 1.f / (1.f + expf(-r0)); r1 = 1.f / (1.f + expf(-r1)); }
        else         { r0 = tanhf(r0);               r1 = tanhf(r1); }
        const float k1 = tanhf(r0), k2 = tanhf(r1);
        float a1 = k1 * (1.f - k2);
        const float a2 = fminf(fmaxf(k2, -0.999f), 0.999f);
        const float bnd = 0.999f - fabsf(a2);
        a1 = fminf(fmaxf(a1, -bnd), bnd);
        const float g = powf(1.f / (1.f + expf(-fg[r][0])), 0.45f);
        const int D1 = md[r] + p + 1;
        const int D2 = md[r] + ((p + 1) % L) + 1;
        const float C1 = a1 * g;
        const float C2 = a2 * g;
        float* cw = cws + r * 32;
        const float bin4[5] = {1.f, 4.f, 6.f, 4.f, 1.f};
        const float c1p[5] = {1.f, C1, C1*C1, C1*C1*C1, C1*C1*C1*C1};
        const float c2p[5] = {1.f, C2, C2*C2, C2*C2*C2, C2*C2*C2*C2};
        for (int j = 0; j < 5; ++j) {
          cw[j]     = (float)((4 - j) * D1 + j * D2);
          cw[5 + j] = bin4[j] * c1p[4 - j] * c2p[j];
        }
        const int   fd[9] = {D1, D2, 2*D1, D1+D2, 2*D2, 3*D1, 2*D1+D2, D1+2*D2, 3*D2};
        const float fn[9] = {-C1, -C2, C1*C1, 2.f*C1*C2, C2*C2,
                             -C1*C1*C1, -3.f*C1*C1*C2, -3.f*C1*C2*C2, -C2*C2*C2};
        for (int k = 0; k < 9; ++k) {
          cw[10 + k] = (float)fd[k];
          cw[19 + k] = fn[k];
        }
      }
      __syncthreads();
    }
  }
}

// ---------------- harmonic synth + banks (memory-bound, float4) --------------
// Block = 4 cylinder-groups x 64 lanes covering 256 samples (4/lane, float4 =
// 16B/lane coalescing sweet spot). Each group: 2 cylinders + 8 noise bands;
// partials combine in LDS; group 0 writes both banks. Grid 512 -> 8 waves/CU;
// unroll-4 keeps ~16 KB of wave-loads in flight (Little's law needs ~9/CU).
__global__ __launch_bounds__(256) void synth_kernel(
    const float* __restrict__ amps,   // (B,512,T)
    const float* __restrict__ fmg,    // (B,1,T)
    const float* __restrict__ cps,    // (B,16,T)
    const float* __restrict__ nba,    // (B,32,T)
    const float* __restrict__ nps,    // (B,2,T)
    const float* __restrict__ npg,    // (B,1,T)
    const float* __restrict__ fng,    // (B,1,T)
    const float* __restrict__ bands,  // (32,T)
    const float* __restrict__ pcp,    // (B,T) ws
    float* __restrict__ bank_a, float* __restrict__ bank_b) {
  const float TPF = 6.283185307179586f;
  const int lane = threadIdx.x & 63;
  const int g    = threadIdx.x >> 6;          // cylinder group 0..3
  const int blk  = blockIdx.x;                // 0..511
  const int b    = blk >> 8;                  // 256 blocks per batch
  const int t    = (blk & 255) * 256 + lane * 4;
  const size_t bt = (size_t)b * T_ + t;

  __shared__ float4 redN[4][64];
  __shared__ float4 redH[4][64];

  const float4 p4 = *(const float4*)(pcp + bt);
  const float4 f4 = *(const float4*)(fmg + bt);

  // noise partial: bands 8g..8g+7
  float4 nse = make_float4(0.f, 0.f, 0.f, 0.f);
#pragma unroll
  for (int j = 0; j < 8; ++j) {
    const int n = g * 8 + j;
    const float4 a = *(const float4*)(nba + ((size_t)b * 32 + n) * T_ + t);
    const float4 w = *(const float4*)(bands + (size_t)n * T_ + t);
    nse.x += a.x * w.x; nse.y += a.y * w.y;
    nse.z += a.z * w.z; nse.w += a.w * w.w;
  }
  redN[g][lane] = nse;

  // harmonics partial: cylinders 2g, 2g+1
  const int order[8] = {0, 4, 3, 7, 5, 2, 6, 1};
  float4 hp = make_float4(0.f, 0.f, 0.f, 0.f);
#pragma unroll
  for (int cc = 0; cc < 2; ++cc) {
    const int c = 2 * g + cc;
    const float ang = ((float)order[c] / 8.0f) * TPF;
#define SETUP(C_)                                                     \
    float s##C_ = p4.C_ + ang; if (s##C_ >= TPF) s##C_ -= TPF;        \
    float sn##C_, cs##C_;                                             \
    sincosf(TPF * powf(s##C_ / TPF, f4.C_), &sn##C_, &cs##C_);        \
    float sp##C_ = 0.f, sc##C_ = sn##C_;                              \
    const float tc##C_ = 2.f * cs##C_;                                \
    float acc##C_ = 0.f;
    SETUP(x) SETUP(y) SETUP(z) SETUP(w)
#undef SETUP
    const float* ap = amps + ((size_t)b * 512 + (size_t)c * 64) * T_ + t;
#pragma unroll 4
    for (int h = 0; h < 64; ++h) {
      const float4 a = *(const float4*)(ap + (size_t)h * T_);
#define HSTEP(C_) {                                                   \
      acc##C_ += a.C_ * sc##C_;                                       \
      const float nx = tc##C_ * sc##C_ - sp##C_;                      \
      sp##C_ = sc##C_; sc##C_ = nx; }
      HSTEP(x) HSTEP(y) HSTEP(z) HSTEP(w)
#undef HSTEP
    }
    const float4 al = *(const float4*)(cps + ((size_t)b * 16 + c) * T_ + t);
    const float4 be = *(const float4*)(cps + ((size_t)b * 16 + 8 + c) * T_ + t);
#define ENVACC(C_) {                                                  \
      const float env = (1.f - expf(-al.C_ * s##C_)) * expf(-be.C_ * s##C_); \
      hp.C_ += -acc##C_ * env * 10.f; }
    ENVACC(x) ENVACC(y) ENVACC(z) ENVACC(w)
#undef ENVACC
  }
  redH[g][lane] = hp;
  __syncthreads();

  if (g == 0) {
    const float4 nA = redN[0][lane], nB = redN[1][lane],
                 nC = redN[2][lane], nD = redN[3][lane];
    const float4 hA0 = redH[0][lane], hA1 = redH[1][lane],
                 hB0 = redH[2][lane], hB1 = redH[3][lane];
    const float4 g4  = *(const float4*)(npg + bt);
    const float4 fl4 = *(const float4*)(fng + bt);
    const float4 na4 = *(const float4*)(nps + (size_t)b * 2 * T_ + t);
    const float4 nb4 = *(const float4*)(nps + ((size_t)b * 2 + 1) * T_ + t);
    float4 outA, outB;
#define FIN(C_) {                                                     \
    const float nse = nA.C_ + nB.C_ + nC.C_ + nD.C_;                  \
    const float ha = hA0.C_ + hA1.C_;                                 \
    const float hb = hB0.C_ + hB1.C_;                                 \
    float q = p4.C_; if (q >= TPF) q -= TPF;                          \
    const float ne = (1.f - expf(-na4.C_ * q)) * expf(-nb4.C_ * q);   \
    const float com = nse * (ne * g4.C_ + fl4.C_ * 0.3f);             \
    const float K = nse * (g4.C_ + fl4.C_) * 0.7f;                    \
    outA.C_ = ha * (1.f + K) + 4.f * com;                             \
    outB.C_ = hb * (1.f + K) + 4.f * com; }
    FIN(x) FIN(y) FIN(z) FIN(w)
#undef FIN
    *(float4*)(bank_a + bt) = outA;
    *(float4*)(bank_b + bt) = outB;
  }
}

// ---------------- feedforward prep: x'' = x + SUM n_k x[t-d_k] --------------
__global__ __launch_bounds__(256) void prep_ab_kernel(
    const float* __restrict__ BA, const float* __restrict__ BB,
    const float* __restrict__ CW, float* __restrict__ XA, float* __restrict__ XB) {
  const int idx = blockIdx.x * 256 + threadIdx.x;   // 0..262143
  const int t = idx & (T_ - 1);
  const int s = idx >> 16;                           // 0..3
  const int r = s >> 1, b = s & 1;
  const float* xin = (r == 0 ? BA : BB) + (size_t)b * T_;
  float* xout = (r == 0 ? XA : XB) + (size_t)b * T_;
  const float* cw = CW + r * 32;
  float acc = xin[t];
#pragma unroll
  for (int k = 0; k < 9; ++k) {
    const int d = (int)cw[10 + k];
    const float n = cw[19 + k];
    const int tc = t - d;
    const float u = xin[tc >= 0 ? tc : 0];
    acc += (tc >= 0) ? n * u : 0.f;
  }
  xout[t] = acc;
}

__global__ __launch_bounds__(256) void prep_c_kernel(
    const float* __restrict__ RA, const float* __restrict__ RB,
    const float* __restrict__ CW, float* __restrict__ XC) {
  const int idx = blockIdx.x * 256 + threadIdx.x;   // 0..131071
  const int t = idx & (T_ - 1);
  const int b = idx >> 16;
  const float* ya = RA + (size_t)b * T_;
  const float* yb = RB + (size_t)b * T_;
  const float* cw = CW + 64;
  float acc = ya[t] + yb[t];
#pragma unroll
  for (int k = 0; k < 9; ++k) {
    const int d = (int)cw[10 + k];
    const float n = cw[19 + k];
    const int tc = t - d;
    const float u = ya[tc >= 0 ? tc : 0] + yb[tc >= 0 ? tc : 0];
    acc += (tc >= 0) ? n * u : 0.f;
  }
  XC[idx] = acc;
}

// ---------------- resonator scan: delay-quadrupled 5-tap recurrence ----------
// One wave per filter, 1024 steps, 2-step-ahead tap prefetch (round 10).
// Round-12: TRIPLE-buffered staging + COUNTED vmcnt. The old per-phase
// vmcnt(0) also waited for the previous phase's 16 y-store acks (~300-500 cy
// exposed per phase). Now each phase ends with s_waitcnt vmcnt(20): newest 20
// VMEM ops = this phase's 16 stores + 4 DMAs of segment ph+2; everything
// older (incl. segment ph+1, issued a phase earlier with ~2000 cy lead) is
// complete. Stores never block; staging has 2 phases of lead > HBM latency.
__device__ __forceinline__ void gld16(const float* g, float* l) {
  __builtin_amdgcn_global_load_lds((const __attribute__((address_space(1))) void*)g,
                                   (__attribute__((address_space(3))) void*)l, 16, 0, 0);
}

__device__ __forceinline__ void poly_scan(const float* __restrict__ x,
                                          float* __restrict__ y,
                                          const float* __restrict__ cf,
                                          float* __restrict__ sm) {
  const int o = threadIdx.x & 63;
  const int e0 = (int)cf[0], e1 = (int)cf[1], e2 = (int)cf[2],
            e3 = (int)cf[3], e4 = (int)cf[4];
  const float fc0 = cf[5], fc1 = cf[6], fc2 = cf[7], fc3 = cf[8], fc4 = cf[9];
  float* ring = sm;          // 1024 floats
  float* st   = sm + 1024;   // 3 x 1024 floats staging

#pragma unroll
  for (int i = 0; i < 16; ++i) ring[o + i * 64] = 0.f;

  // stage segments 0,1 -> buffers 0,1
#pragma unroll
  for (int seg = 0; seg < 2; ++seg) {
    const float* g = x + seg * 1024 + (o << 2);
    float* l = st + seg * 1024;
    gld16(g, l); gld16(g + 256, l + 256);
    gld16(g + 512, l + 512); gld16(g + 768, l + 768);
  }
  // wait for segment 0 only (newest 4 = segment 1's DMAs)
  asm volatile("s_waitcnt vmcnt(4)" ::: "memory");

  float a0 = ring[(o - e0) & 1023];
  float a1v = ring[(o - e1) & 1023];
  float a2v = ring[(o - e2) & 1023];
  float a3v = ring[(o - e3) & 1023];
  float a4v = ring[(o - e4) & 1023];
  float b0 = ring[(o + 64 - e0) & 1023];
  float b1v = ring[(o + 64 - e1) & 1023];
  float b2v = ring[(o + 64 - e2) & 1023];
  float b3v = ring[(o + 64 - e3) & 1023];
  float b4v = ring[(o + 64 - e4) & 1023];

  int t = o;
  int bufsel = 0;
  for (int ph = 0; ph < 64; ++ph) {
    if (ph < 62) {   // stage segment ph+2 into the free buffer
      const int seg = ph + 2;
      const float* g = x + seg * 1024 + (o << 2);
      float* l = st + (seg - (seg / 3) * 3) * 1024;
      gld16(g, l); gld16(g + 256, l + 256);
      gld16(g + 512, l + 512); gld16(g + 768, l + 768);
    }
    const float* bq = st + bufsel * 1024;
    bufsel = (bufsel == 2) ? 0 : (bufsel + 1);
    float xv0 = bq[o];
    float xv1 = bq[64 + o];
#pragma unroll
    for (int l = 0; l < 16; l += 2) {
      {
        const float s01 = fmaf(fc0, a0, fc1 * a1v);
        const float s23 = fmaf(fc2, a2v, fc3 * a3v);
        const float yv = xv0 + (s01 + fmaf(fc4, a4v, s23));
        ring[t & 1023] = yv;
        y[t] = yv;
        a0  = ring[(t + 128 - e0) & 1023];
        a1v = ring[(t + 128 - e1) & 1023];
        a2v = ring[(t + 128 - e2) & 1023];
        a3v = ring[(t + 128 - e3) & 1023];
        a4v = ring[(t + 128 - e4) & 1023];
        if (l + 2 < 16) xv0 = bq[(l + 2) * 64 + o];
        t += 64;
      }
      {
        const float s01 = fmaf(fc0, b0, fc1 * b1v);
        const float s23 = fmaf(fc2, b2v, fc3 * b3v);
        const float yv = xv1 + (s01 + fmaf(fc4, b4v, s23));
        ring[t & 1023] = yv;
        y[t] = yv;
        b0  = ring[(t + 128 - e0) & 1023];
        b1v = ring[(t + 128 - e1) & 1023];
        b2v = ring[(t + 128 - e2) & 1023];
        b3v = ring[(t + 128 - e3) & 1023];
        b4v = ring[(t + 128 - e4) & 1023];
        if (l + 3 < 16) xv1 = bq[(l + 3) * 64 + o];
        t += 64;
      }
    }
    // counted drain: next segment (issued a phase ago) is complete once all
    // but the newest 20 (16 stores + 4 fresh DMAs) have retired.
    asm volatile("s_waitcnt vmcnt(20)" ::: "memory");
  }
}

__global__ __launch_bounds__(64) void res_ab_kernel(
    const float* __restrict__ XA, const float* __restrict__ XB,
    float* __restrict__ RA, float* __restrict__ RB, const float* __restrict__ CW) {
  __shared__ float sm[4096];
  const int r = blockIdx.x >> 1;
  const int b = blockIdx.x & 1;
  poly_scan((r == 0 ? XA : XB) + (size_t)b * T_,
            (r == 0 ? RA : RB) + (size_t)b * T_, CW + r * 32, sm);
}

__global__ __launch_bounds__(64) void res_c_kernel(
    const float* __restrict__ XC, float* __restrict__ out,
    const float* __restrict__ CW) {
  __shared__ float sm[4096];
  poly_scan(XC + (size_t)blockIdx.x * T_, out + (size_t)blockIdx.x * T_,
            CW + 64, sm);
}

// ---------------- launch ----------------
extern "C" void kernel_launch(void* const* d_in, const int* in_sizes, int n_in,
                              void* d_out, int out_size, void* d_ws, size_t ws_size,
                              hipStream_t stream) {
  const float* f0    = (const float*)d_in[0];
  const float* amps  = (const float*)d_in[1];
  const float* fmg   = (const float*)d_in[2];
  const float* cps   = (const float*)d_in[4];
  const float* nba   = (const float*)d_in[5];
  const float* nps   = (const float*)d_in[6];
  const float* npg   = (const float*)d_in[7];
  const float* fng   = (const float*)d_in[8];
  const float* bands = (const float*)d_in[9];
  const float* da  = (const float*)d_in[10];
  const float* fga = (const float*)d_in[11];
  const float* ra  = (const float*)d_in[12];
  const float* db  = (const float*)d_in[13];
  const float* fgb = (const float*)d_in[14];
  const float* rb  = (const float*)d_in[15];
  const float* dc  = (const float*)d_in[16];
  const float* fgc = (const float*)d_in[17];
  const float* rc  = (const float*)d_in[18];
  float* out = (float*)d_out;
  float* ws  = (float*)d_ws;

  // slots of 131072 floats (B*T):
  float* S0 = ws;              // pcp  -> later XA (x''_a)
  float* S1 = ws + 131072;     // bank_a -> later RA (res_a)
  float* S2 = ws + 262144;     // bank_b -> later RB (res_b)
  float* S3 = ws + 393216;     // XB (x''_b) -> later XC (x''_c)
  float* CW = ws + 524288;     // coefficients (96 floats)

  pcp_coef_kernel<<<3, 1024, 0, stream>>>(f0, S0, da, fga, ra, db, fgb, rb,
                                          dc, fgc, rc, CW);
  synth_kernel<<<512, 256, 0, stream>>>(amps, fmg, cps, nba, nps, npg, fng, bands,
                                        S0, S1, S2);
  // feedforward for banks: XA<-S0 (pcp dead), XB<-S3; reads banks S1,S2
  prep_ab_kernel<<<1024, 256, 0, stream>>>(S1, S2, CW, S0, S3);
  // scans: RA->S1 (bank_a dead), RB->S2 (bank_b dead); reads XA=S0, XB=S3
  res_ab_kernel<<<4, 64, 0, stream>>>(S0, S3, S1, S2, CW);
  // feedforward for c: XC<-S3 (XB dead); reads RA=S1, RB=S2
  prep_c_kernel<<<512, 256, 0, stream>>>(S1, S2, CW, S3);
  res_c_kernel<<<2, 64, 0, stream>>>(S3, out, CW);
}

// Round 13
// 248.653 us; speedup vs baseline: 3.7221x; 1.0247x over previous
//
#include <hip/hip_runtime.h>
#include <cstdint>
#include <cstddef>

#define T_ 65536

// ---------------- threefry2x32 (bit-exact vs JAX) ----------------
__device__ __forceinline__ void tf2x32(uint32_t k0, uint32_t k1,
                                       uint32_t& x0, uint32_t& x1) {
  const uint32_t ks[3] = {k0, k1, k0 ^ k1 ^ 0x1BD11BDAu};
  const int R[8] = {13, 15, 26, 6, 17, 29, 16, 24};
  x0 += ks[0]; x1 += ks[1];
#pragma unroll
  for (int i = 0; i < 5; ++i) {
#pragma unroll
    for (int j = 0; j < 4; ++j) {
      const int r = R[(i & 1) * 4 + j];
      x0 += x1;
      x1 = (x1 << r) | (x1 >> (32 - r));
      x1 ^= x0;
    }
    x0 += ks[(i + 1) % 3];
    x1 += ks[(i + 2) % 3] + (uint32_t)(i + 1);
  }
}

__device__ __forceinline__ float gumbel_from_bits(uint32_t b) {
  float u = __uint_as_float((b >> 9) | 0x3f800000u) - 1.0f;
  u = fmaxf(u, 1.17549435e-38f);
  return -logf(-logf(u));
}

// ---------------- fused pcp prefix-scan (blocks 0,1) + coef setup (block 2) --
__global__ __launch_bounds__(1024) void pcp_coef_kernel(
    const float* __restrict__ f0, float* __restrict__ pcp,
    const float* __restrict__ da, const float* __restrict__ fa, const float* __restrict__ ra,
    const float* __restrict__ db, const float* __restrict__ fb, const float* __restrict__ rb,
    const float* __restrict__ dc, const float* __restrict__ fc, const float* __restrict__ rc,
    float* __restrict__ cws) {
  __shared__ double sm[1024];
  __shared__ float z[128];
  if (blockIdx.x < 2) {
    const int b = blockIdx.x;
    const int tid = threadIdx.x;
    const float* src = f0 + (size_t)b * T_;
    const int base = tid * 64;
    double loc = 0.0;
#pragma unroll 4
    for (int k = 0; k < 16; ++k) {
      const float4 a = *(const float4*)(src + base + 4 * k);
      loc += 6.283185307179586 * (double)a.x / 48000.0;
      loc += 6.283185307179586 * (double)a.y / 48000.0;
      loc += 6.283185307179586 * (double)a.z / 48000.0;
      loc += 6.283185307179586 * (double)a.w / 48000.0;
    }
    sm[tid] = loc;
    __syncthreads();
    for (int off = 1; off < 1024; off <<= 1) {
      double v = (tid >= off) ? sm[tid - off] : 0.0;
      __syncthreads();
      sm[tid] += v;
      __syncthreads();
    }
    double run = (tid > 0) ? sm[tid - 1] : 0.0;
    float* dst = pcp + (size_t)b * T_;
#pragma unroll 4
    for (int k = 0; k < 16; ++k) {
      const float4 a = *(const float4*)(src + base + 4 * k);
      const double r0 = run + 6.283185307179586 * (double)a.x / 48000.0;
      const double r1 = r0  + 6.283185307179586 * (double)a.y / 48000.0;
      const double r2 = r1  + 6.283185307179586 * (double)a.z / 48000.0;
      const double r3 = r2  + 6.283185307179586 * (double)a.w / 48000.0;
      *(float4*)(dst + base + 4 * k) = make_float4((float)(r0 * 0.5), (float)(r1 * 0.5),
                                                   (float)(r2 * 0.5), (float)(r3 * 0.5));
      run = r3;
    }
  } else {
    uint32_t keys[3][2];
#pragma unroll
    for (int q = 0; q < 3; ++q) {
      uint32_t x0 = 0u, x1 = (uint32_t)q;
      tf2x32(0u, 42u, x0, x1);
      keys[q][0] = x0; keys[q][1] = x1;
    }
    const float* dl[3] = {da, db, dc};
    const float* fg[3] = {fa, fb, fc};
    const float* rf[3] = {ra, rb, rc};
    const int Ls[3] = {85, 85, 8};
    const int md[3] = {40, 40, 32};
    const int i = threadIdx.x;
    for (int r = 0; r < 3; ++r) {
      const int L = Ls[r];
      if (i < 128) z[i] = -3.4e38f;
      __syncthreads();
      if (i < L) {
        uint32_t x0 = 0u, x1 = (uint32_t)i;
        tf2x32(keys[r][0], keys[r][1], x0, x1);
        z[i] = dl[r][i] + gumbel_from_bits(x0 ^ x1);
      }
      __syncthreads();
      if (i == 0) {
        int p = 0; float best = z[0];
        for (int j = 1; j < L; ++j) { float v = z[j]; if (v > best) { best = v; p = j; } }
        const bool lowpass = (r == 2);
        float r0 = rf[r][0], r1 = rf[r][1];
        if (lowpass) { r0 = 1.f / (1.f + expf(-r0)); r1 = 1.f / (1.f + expf(-r1)); }
        else         { r0 = tanhf(r0);               r1 = tanhf(r1); }
        const float k1 = tanhf(r0), k2 = tanhf(r1);
        float a1 = k1 * (1.f - k2);
        const float a2 = fminf(fmaxf(k2, -0.999f), 0.999f);
        const float bnd = 0.999f - fabsf(a2);
        a1 = fminf(fmaxf(a1, -bnd), bnd);
        const float g = powf(1.f / (1.f + expf(-fg[r][0])), 0.45f);
        const int D1 = md[r] + p + 1;
        const int D2 = md[r] + ((p + 1) % L) + 1;
        const float C1 = a1 * g;
        const float C2 = a2 * g;
        float* cw = cws + r * 32;
        const float bin4[5] = {1.f, 4.f, 6.f, 4.f, 1.f};
        const float c1p[5] = {1.f, C1, C1*C1, C1*C1*C1, C1*C1*C1*C1};
        const float c2p[5] = {1.f, C2, C2*C2, C2*C2*C2, C2*C2*C2*C2};
        for (int j = 0; j < 5; ++j) {
          cw[j]     = (float)((4 - j) * D1 + j * D2);
          cw[5 + j] = bin4[j] * c1p[4 - j] * c2p[j];
        }
        const int   fd[9] = {D1, D2, 2*D1, D1+D2, 2*D2, 3*D1, 2*D1+D2, D1+2*D2, 3*D2};
        const float fn[9] = {-C1, -C2, C1*C1, 2.f*C1*C2, C2*C2,
                             -C1*C1*C1, -3.f*C1*C1*C2, -3.f*C1*C2*C2, -C2*C2*C2};
        for (int k = 0; k < 9; ++k) {
          cw[10 + k] = (float)fd[k];
          cw[19 + k] = fn[k];
        }
      }
      __syncthreads();
    }
  }
}

// ---------------- harmonic synth + banks (memory-bound, float4) --------------
__global__ __launch_bounds__(256) void synth_kernel(
    const float* __restrict__ amps,   // (B,512,T)
    const float* __restrict__ fmg,    // (B,1,T)
    const float* __restrict__ cps,    // (B,16,T)
    const float* __restrict__ nba,    // (B,32,T)
    const float* __restrict__ nps,    // (B,2,T)
    const float* __restrict__ npg,    // (B,1,T)
    const float* __restrict__ fng,    // (B,1,T)
    const float* __restrict__ bands,  // (32,T)
    const float* __restrict__ pcp,    // (B,T) ws
    float* __restrict__ bank_a, float* __restrict__ bank_b) {
  const float TPF = 6.283185307179586f;
  const int lane = threadIdx.x & 63;
  const int g    = threadIdx.x >> 6;          // cylinder group 0..3
  const int blk  = blockIdx.x;                // 0..511
  const int b    = blk >> 8;                  // 256 blocks per batch
  const int t    = (blk & 255) * 256 + lane * 4;
  const size_t bt = (size_t)b * T_ + t;

  __shared__ float4 redN[4][64];
  __shared__ float4 redH[4][64];

  const float4 p4 = *(const float4*)(pcp + bt);
  const float4 f4 = *(const float4*)(fmg + bt);

  float4 nse = make_float4(0.f, 0.f, 0.f, 0.f);
#pragma unroll
  for (int j = 0; j < 8; ++j) {
    const int n = g * 8 + j;
    const float4 a = *(const float4*)(nba + ((size_t)b * 32 + n) * T_ + t);
    const float4 w = *(const float4*)(bands + (size_t)n * T_ + t);
    nse.x += a.x * w.x; nse.y += a.y * w.y;
    nse.z += a.z * w.z; nse.w += a.w * w.w;
  }
  redN[g][lane] = nse;

  const int order[8] = {0, 4, 3, 7, 5, 2, 6, 1};
  float4 hp = make_float4(0.f, 0.f, 0.f, 0.f);
#pragma unroll
  for (int cc = 0; cc < 2; ++cc) {
    const int c = 2 * g + cc;
    const float ang = ((float)order[c] / 8.0f) * TPF;
#define SETUP(C_)                                                     \
    float s##C_ = p4.C_ + ang; if (s##C_ >= TPF) s##C_ -= TPF;        \
    float sn##C_, cs##C_;                                             \
    sincosf(TPF * powf(s##C_ / TPF, f4.C_), &sn##C_, &cs##C_);        \
    float sp##C_ = 0.f, sc##C_ = sn##C_;                              \
    const float tc##C_ = 2.f * cs##C_;                                \
    float acc##C_ = 0.f;
    SETUP(x) SETUP(y) SETUP(z) SETUP(w)
#undef SETUP
    const float* ap = amps + ((size_t)b * 512 + (size_t)c * 64) * T_ + t;
#pragma unroll 4
    for (int h = 0; h < 64; ++h) {
      const float4 a = *(const float4*)(ap + (size_t)h * T_);
#define HSTEP(C_) {                                                   \
      acc##C_ += a.C_ * sc##C_;                                       \
      const float nx = tc##C_ * sc##C_ - sp##C_;                      \
      sp##C_ = sc##C_; sc##C_ = nx; }
      HSTEP(x) HSTEP(y) HSTEP(z) HSTEP(w)
#undef HSTEP
    }
    const float4 al = *(const float4*)(cps + ((size_t)b * 16 + c) * T_ + t);
    const float4 be = *(const float4*)(cps + ((size_t)b * 16 + 8 + c) * T_ + t);
#define ENVACC(C_) {                                                  \
      const float env = (1.f - expf(-al.C_ * s##C_)) * expf(-be.C_ * s##C_); \
      hp.C_ += -acc##C_ * env * 10.f; }
    ENVACC(x) ENVACC(y) ENVACC(z) ENVACC(w)
#undef ENVACC
  }
  redH[g][lane] = hp;
  __syncthreads();

  if (g == 0) {
    const float4 nA = redN[0][lane], nB = redN[1][lane],
                 nC = redN[2][lane], nD = redN[3][lane];
    const float4 hA0 = redH[0][lane], hA1 = redH[1][lane],
                 hB0 = redH[2][lane], hB1 = redH[3][lane];
    const float4 g4  = *(const float4*)(npg + bt);
    const float4 fl4 = *(const float4*)(fng + bt);
    const float4 na4 = *(const float4*)(nps + (size_t)b * 2 * T_ + t);
    const float4 nb4 = *(const float4*)(nps + ((size_t)b * 2 + 1) * T_ + t);
    float4 outA, outB;
#define FIN(C_) {                                                     \
    const float nse = nA.C_ + nB.C_ + nC.C_ + nD.C_;                  \
    const float ha = hA0.C_ + hA1.C_;                                 \
    const float hb = hB0.C_ + hB1.C_;                                 \
    float q = p4.C_; if (q >= TPF) q -= TPF;                          \
    const float ne = (1.f - expf(-na4.C_ * q)) * expf(-nb4.C_ * q);   \
    const float com = nse * (ne * g4.C_ + fl4.C_ * 0.3f);             \
    const float K = nse * (g4.C_ + fl4.C_) * 0.7f;                    \
    outA.C_ = ha * (1.f + K) + 4.f * com;                             \
    outB.C_ = hb * (1.f + K) + 4.f * com; }
    FIN(x) FIN(y) FIN(z) FIN(w)
#undef FIN
    *(float4*)(bank_a + bt) = outA;
    *(float4*)(bank_b + bt) = outB;
  }
}

// ---------------- feedforward prep: x'' = x + SUM n_k x[t-d_k] --------------
__global__ __launch_bounds__(256) void prep_ab_kernel(
    const float* __restrict__ BA, const float* __restrict__ BB,
    const float* __restrict__ CW, float* __restrict__ XA, float* __restrict__ XB) {
  const int idx = blockIdx.x * 256 + threadIdx.x;   // 0..262143
  const int t = idx & (T_ - 1);
  const int s = idx >> 16;                           // 0..3
  const int r = s >> 1, b = s & 1;
  const float* xin = (r == 0 ? BA : BB) + (size_t)b * T_;
  float* xout = (r == 0 ? XA : XB) + (size_t)b * T_;
  const float* cw = CW + r * 32;
  float acc = xin[t];
#pragma unroll
  for (int k = 0; k < 9; ++k) {
    const int d = (int)cw[10 + k];
    const float n = cw[19 + k];
    const int tc = t - d;
    const float u = xin[tc >= 0 ? tc : 0];
    acc += (tc >= 0) ? n * u : 0.f;
  }
  xout[t] = acc;
}

__global__ __launch_bounds__(256) void prep_c_kernel(
    const float* __restrict__ RA, const float* __restrict__ RB,
    const float* __restrict__ CW, float* __restrict__ XC) {
  const int idx = blockIdx.x * 256 + threadIdx.x;   // 0..131071
  const int t = idx & (T_ - 1);
  const int b = idx >> 16;
  const float* ya = RA + (size_t)b * T_;
  const float* yb = RB + (size_t)b * T_;
  const float* cw = CW + 64;
  float acc = ya[t] + yb[t];
#pragma unroll
  for (int k = 0; k < 9; ++k) {
    const int d = (int)cw[10 + k];
    const float n = cw[19 + k];
    const int tc = t - d;
    const float u = ya[tc >= 0 ? tc : 0] + yb[tc >= 0 ? tc : 0];
    acc += (tc >= 0) ? n * u : 0.f;
  }
  XC[idx] = acc;
}

// ---------------- resonator scan: delay-quadrupled 5-tap recurrence ----------
// Round-13 scan: 128 samples/iteration (valid: all E >= 132 > 128+4, so both
// halves' taps -- prefetched one iteration ahead -- are final before the iter
// starts), 512 iterations. Per-step global stores removed: the 1024-float ring
// IS the phase's output (phases are 1024-aligned) -> flushed once per phase
// with 4x ds_read_b128 + 4x global_store_dwordx4. Counted s_waitcnt vmcnt(8)
// per phase (newest 8 = 4 bulk stores + 4 DMAs of segment ph+2) guarantees
// segment ph+1 (issued a full phase earlier) is resident.
__device__ __forceinline__ void gld16(const float* g, float* l) {
  __builtin_amdgcn_global_load_lds((const __attribute__((address_space(1))) void*)g,
                                   (__attribute__((address_space(3))) void*)l, 16, 0, 0);
}

__device__ __forceinline__ void poly_scan(const float* __restrict__ x,
                                          float* __restrict__ y,
                                          const float* __restrict__ cf,
                                          float* __restrict__ sm) {
  const int o = threadIdx.x & 63;
  const int e0 = (int)cf[0], e1 = (int)cf[1], e2 = (int)cf[2],
            e3 = (int)cf[3], e4 = (int)cf[4];
  const float fc0 = cf[5], fc1 = cf[6], fc2 = cf[7], fc3 = cf[8], fc4 = cf[9];
  float* ring = sm;          // 1024 floats
  float* st   = sm + 1024;   // 3 x 1024 floats staging

#pragma unroll
  for (int i = 0; i < 16; ++i) ring[o + i * 64] = 0.f;

  // stage segments 0,1 -> buffers 0,1
#pragma unroll
  for (int seg = 0; seg < 2; ++seg) {
    const float* g = x + seg * 1024 + (o << 2);
    float* l = st + seg * 1024;
    gld16(g, l); gld16(g + 256, l + 256);
    gld16(g + 512, l + 512); gld16(g + 768, l + 768);
  }
  asm volatile("s_waitcnt vmcnt(4)" ::: "memory");   // segment 0 resident
  __builtin_amdgcn_sched_barrier(0);

  // prime taps for iteration 0 (halves at t=o and t=o+64); reads pre-zeroed
  // slots that are not rewritten before use.
  float a0 = ring[(o - e0) & 1023];
  float a1v = ring[(o - e1) & 1023];
  float a2v = ring[(o - e2) & 1023];
  float a3v = ring[(o - e3) & 1023];
  float a4v = ring[(o - e4) & 1023];
  float b0 = ring[(o + 64 - e0) & 1023];
  float b1v = ring[(o + 64 - e1) & 1023];
  float b2v = ring[(o + 64 - e2) & 1023];
  float b3v = ring[(o + 64 - e3) & 1023];
  float b4v = ring[(o + 64 - e4) & 1023];

  int m = 0;   // sample base of current 128-sample iteration
  for (int ph = 0; ph < 64; ++ph) {
    if (ph < 62) {   // stage segment ph+2 into the free buffer
      const int seg = ph + 2;
      const float* g = x + seg * 1024 + (o << 2);
      float* l = st + (seg % 3) * 1024;
      gld16(g, l); gld16(g + 256, l + 256);
      gld16(g + 512, l + 512); gld16(g + 768, l + 768);
    }
    const float* bq = st + (ph % 3) * 1024;
    float xv0 = bq[o];
    float xv1 = bq[64 + o];
#pragma unroll
    for (int li = 0; li < 8; ++li) {
      // half 0 (samples m..m+63)
      const float sA = fmaf(fc0, a0, fc1 * a1v) + fmaf(fc2, a2v, fc3 * a3v);
      const float y0 = xv0 + fmaf(fc4, a4v, sA);
      ring[(m + o) & 1023] = y0;
      // half 1 (samples m+64..m+127): taps prefetched last iter, targets <= m-5
      const float sB = fmaf(fc0, b0, fc1 * b1v) + fmaf(fc2, b2v, fc3 * b3v);
      const float y1 = xv1 + fmaf(fc4, b4v, sB);
      ring[(m + 64 + o) & 1023] = y1;
      // prefetch taps for next iteration (m+128): targets <= m+59, written
      // this iteration or earlier (in-order DS within the wave).
      a0  = ring[(m + 128 + o - e0) & 1023];
      a1v = ring[(m + 128 + o - e1) & 1023];
      a2v = ring[(m + 128 + o - e2) & 1023];
      a3v = ring[(m + 128 + o - e3) & 1023];
      a4v = ring[(m + 128 + o - e4) & 1023];
      b0  = ring[(m + 192 + o - e0) & 1023];
      b1v = ring[(m + 192 + o - e1) & 1023];
      b2v = ring[(m + 192 + o - e2) & 1023];
      b3v = ring[(m + 192 + o - e3) & 1023];
      b4v = ring[(m + 192 + o - e4) & 1023];
      if (li < 7) { xv0 = bq[(li + 1) * 128 + o]; xv1 = bq[(li + 1) * 128 + 64 + o]; }
      m += 128;
    }
    // bulk-flush the phase's 1024 y values from the ring (ring slot k holds
    // y[ph*1024 + k] exactly -- phases are 1024-aligned).
#pragma unroll
    for (int j = 0; j < 4; ++j) {
      const float4 v = *(const float4*)(ring + (o << 2) + j * 256);
      *(float4*)(y + ph * 1024 + j * 256 + (o << 2)) = v;
    }
    asm volatile("s_waitcnt vmcnt(8)" ::: "memory");
    __builtin_amdgcn_sched_barrier(0);
  }
}

__global__ __launch_bounds__(64) void res_ab_kernel(
    const float* __restrict__ XA, const float* __restrict__ XB,
    float* __restrict__ RA, float* __restrict__ RB, const float* __restrict__ CW) {
  __shared__ float sm[4096];
  const int r = blockIdx.x >> 1;
  const int b = blockIdx.x & 1;
  poly_scan((r == 0 ? XA : XB) + (size_t)b * T_,
            (r == 0 ? RA : RB) + (size_t)b * T_, CW + r * 32, sm);
}

__global__ __launch_bounds__(64) void res_c_kernel(
    const float* __restrict__ XC, float* __restrict__ out,
    const float* __restrict__ CW) {
  __shared__ float sm[4096];
  poly_scan(XC + (size_t)blockIdx.x * T_, out + (size_t)blockIdx.x * T_,
            CW + 64, sm);
}

// ---------------- launch ----------------
extern "C" void kernel_launch(void* const* d_in, const int* in_sizes, int n_in,
                              void* d_out, int out_size, void* d_ws, size_t ws_size,
                              hipStream_t stream) {
  const float* f0    = (const float*)d_in[0];
  const float* amps  = (const float*)d_in[1];
  const float* fmg   = (const float*)d_in[2];
  const float* cps   = (const float*)d_in[4];
  const float* nba   = (const float*)d_in[5];
  const float* nps   = (const float*)d_in[6];
  const float* npg   = (const float*)d_in[7];
  const float* fng   = (const float*)d_in[8];
  const float* bands = (const float*)d_in[9];
  const float* da  = (const float*)d_in[10];
  const float* fga = (const float*)d_in[11];
  const float* ra  = (const float*)d_in[12];
  const float* db  = (const float*)d_in[13];
  const float* fgb = (const float*)d_in[14];
  const float* rb  = (const float*)d_in[15];
  const float* dc  = (const float*)d_in[16];
  const float* fgc = (const float*)d_in[17];
  const float* rc  = (const float*)d_in[18];
  float* out = (float*)d_out;
  float* ws  = (float*)d_ws;

  // slots of 131072 floats (B*T):
  float* S0 = ws;              // pcp  -> later XA (x''_a)
  float* S1 = ws + 131072;     // bank_a -> later RA (res_a)
  float* S2 = ws + 262144;     // bank_b -> later RB (res_b)
  float* S3 = ws + 393216;     // XB (x''_b) -> later XC (x''_c)
  float* CW = ws + 524288;     // coefficients (96 floats)

  pcp_coef_kernel<<<3, 1024, 0, stream>>>(f0, S0, da, fga, ra, db, fgb, rb,
                                          dc, fgc, rc, CW);
  synth_kernel<<<512, 256, 0, stream>>>(amps, fmg, cps, nba, nps, npg, fng, bands,
                                        S0, S1, S2);
  // feedforward for banks: XA<-S0 (pcp dead), XB<-S3; reads banks S1,S2
  prep_ab_kernel<<<1024, 256, 0, stream>>>(S1, S2, CW, S0, S3);
  // scans: RA->S1 (bank_a dead), RB->S2 (bank_b dead); reads XA=S0, XB=S3
  res_ab_kernel<<<4, 64, 0, stream>>>(S0, S3, S1, S2, CW);
  // feedforward for c: XC<-S3 (XB dead); reads RA=S1, RB=S2
  prep_c_kernel<<<512, 256, 0, stream>>>(S1, S2, CW, S3);
  res_c_kernel<<<2, 64, 0, stream>>>(S3, out, CW);
}